// Round 13
// baseline (653.619 us; speedup 1.0000x reference)
//
#include <hip/hip_runtime.h>

typedef unsigned short u16;
typedef unsigned int u32;
typedef __attribute__((ext_vector_type(8))) short s16x8;
typedef __attribute__((ext_vector_type(4))) float f32x4;

#define NN 10000
#define EE 200000
#define ES ((size_t)EE * 64)
#define NTILE 3125

#define DEVI __device__ __forceinline__

DEVI float us2f(u16 u) {
    union { u32 i; float f; } v; v.i = ((u32)u) << 16; return v.f;
}
DEVI u16 f2bu(float f) {
    union { float f; u32 i; } v; v.f = f;
    u32 x = v.i;
    return (u16)((x + 0x7fffu + ((x >> 16) & 1u)) >> 16);
}
DEVI float siluf(float x) { return x / (1.f + __expf(-x)); }
DEVI float sigmf(float x) { return 1.f / (1.f + __expf(-x)); }
DEVI float waveSum(float v) {
#pragma unroll
    for (int o = 32; o; o >>= 1) v += __shfl_xor(v, o);
    return v;
}
DEVI float quadSum(float v) {
#pragma unroll
    for (int o = 1; o < 16; o <<= 1) v += __shfl_xor(v, o);
    return v;
}

// ---- module-owned scratch ----
__device__ u16 g_hb[(size_t)NN * 64];
__device__ u16 g_nab[(size_t)NN * 64];
__device__ u16 g_eab[(size_t)EE * 16];
__device__ u16 g_t1[ES];
__device__ u16 g_z16[ES];
__device__ u16 g_t4[4][ES];
__device__ __align__(16) u16 g_Mt[4][4608];     // [hd][n*72+k] bf16 pre-transposed Wq@Wk^T
__device__ __align__(16) u16 g_wpre[12][4608];  // [hd*3+{V,O,G}][n*72+k] bf16 pre-transposed
__device__ __align__(16) u16 g_wmA[6][4608];    // megaAB: posW2,chW2,shW,uW1,xW1,nW1 pre-transposed
__device__ __align__(16) u16 g_w1t[64 * 296];   // chem1 B^T (bf16, padded K to 296)
__device__ float g_b4[(size_t)EE * 4];
__device__ float g_nr[EE];
__device__ float g_rad[EE];
__device__ float g_cdl[EE * 3];
// CSR aggregation
__device__ int g_degi[NN];
__device__ int g_fill[NN];
__device__ int g_roff[NN + 1];
__device__ int g_eid[EE];
__device__ float g_me[(size_t)EE * 64];   // per-edge m rows (fp32)
__device__ float g_xe[EE * 3];
__device__ float g_ne[EE * 3];
__device__ float g_mavg[(size_t)NN * 64];

// ---------------- zero CSR counters ----------------
__global__ __launch_bounds__(256) void k_zero()
{
    int t = blockIdx.x * 256 + threadIdx.x;
    if (t < NN) { g_degi[t] = 0; g_fill[t] = 0; }
}

// ---------------- prep: Mt, weight pre-convert (heads + megaAB + chem1), bf16, geometry, deg ----------------
__global__ __launch_bounds__(256) void k_prep(
    const float* __restrict__ Wq, const float* __restrict__ Wk,
    const float* __restrict__ h, const float* __restrict__ na, const float* __restrict__ ea,
    const float* __restrict__ coord, const float* __restrict__ nvecs,
    const float* __restrict__ Wv, const float* __restrict__ Wg, const float* __restrict__ oW,
    const float* __restrict__ posW2, const float* __restrict__ chW2, const float* __restrict__ shW,
    const float* __restrict__ uW1, const float* __restrict__ xW1, const float* __restrict__ nW1,
    const float* __restrict__ chemW1,
    const int* __restrict__ edges)
{
    int t = blockIdx.x * 256 + threadIdx.x;
    if (t < 16384) {
        int hd = t >> 12, rem = t & 4095, k = rem >> 6, n = rem & 63;
        const float* wq = Wq + (size_t)hd * 4096 + k * 64;
        const float* wk = Wk + (size_t)hd * 4096 + n * 64;
        float acc = 0.f;
        for (int d = 0; d < 64; d++) acc += wq[d] * wk[d];
        int off = n * 72 + k;
        g_Mt[hd][off] = f2bu(acc);
        g_wpre[hd * 3 + 0][off] = f2bu(Wv[t]);
        g_wpre[hd * 3 + 1][off] = f2bu(oW[t]);
        g_wpre[hd * 3 + 2][off] = f2bu(Wg[t]);
    }
    int nt = gridDim.x * 256;
    // megaAB weights: pre-transposed bf16 [n*72+k]
    for (int i = t; i < 6 * 4096; i += nt) {
        int a = i >> 12, rem = i & 4095, k = rem >> 6, n = rem & 63;
        const float* s;
        if (a == 0) s = posW2;
        else if (a == 1) s = chW2;
        else if (a == 2) s = shW;
        else if (a == 3) s = uW1;
        else if (a == 4) s = xW1;
        else s = nW1;
        g_wmA[a][n * 72 + k] = f2bu(s[rem]);
    }
    // chem1 B^T, K padded to 296
    for (int i = t; i < 64 * 296; i += nt) {
        int n = i / 296, k = i - n * 296;
        g_w1t[i] = (k < 272) ? f2bu(chemW1[k * 64 + n]) : (u16)0;
    }
    for (int i = t; i < NN * 64; i += nt) { g_hb[i] = f2bu(h[i]); g_nab[i] = f2bu(na[i]); }
    for (size_t i = t; i < (size_t)EE * 16; i += nt) g_eab[i] = f2bu(ea[i]);
    for (int e = t; e < EE; e += nt) {
        int r = edges[e], c = edges[EE + e];
        atomicAdd(&g_degi[r], 1);
        float d0 = coord[r * 3 + 0] - coord[c * 3 + 0];
        float d1 = coord[r * 3 + 1] - coord[c * 3 + 1];
        float d2 = coord[r * 3 + 2] - coord[c * 3 + 2];
        float radial = d0 * d0 + d1 * d1 + d2 * d2;
        float np = nvecs[r * 3 + 0] * nvecs[c * 3 + 0]
                 + nvecs[r * 3 + 1] * nvecs[c * 3 + 1]
                 + nvecs[r * 3 + 2] * nvecs[c * 3 + 2];
        float rinv = 1.f / (sqrtf(radial) + 1e-8f);
        g_cdl[e * 3 + 0] = d0 * rinv;
        g_cdl[e * 3 + 1] = d1 * rinv;
        g_cdl[e * 3 + 2] = d2 * rinv;
        g_nr[e] = np;
        g_rad[e] = radial;
    }
}

// ---------------- exclusive scan of degrees (1 block) ----------------
__global__ __launch_bounds__(256) void k_scan()
{
    __shared__ int ls[256];
    int tid = threadIdx.x;
    int basei = tid * 40;
    int loc[40];
    int cnt = 0;
#pragma unroll
    for (int i = 0; i < 40; i++) {
        int idx = basei + i;
        int v = (idx < NN) ? g_degi[idx] : 0;
        loc[i] = cnt; cnt += v;
    }
    ls[tid] = cnt;
    __syncthreads();
    int off = 0;
    for (int i = 0; i < tid; i++) off += ls[i];
#pragma unroll
    for (int i = 0; i < 40; i++) {
        int idx = basei + i;
        if (idx < NN) g_roff[idx] = off + loc[i];
    }
    if (tid == 255) g_roff[NN] = off + cnt;
}

// ---------------- CSR fill ----------------
__global__ __launch_bounds__(256) void k_fill(const int* __restrict__ edges)
{
    int e = blockIdx.x * 256 + threadIdx.x;
    if (e < EE) {
        int r = edges[e];
        int slot = atomicAdd(&g_fill[r], 1);
        g_eid[g_roff[r] + slot] = e;
    }
}

// ---------------- chem layer1: gathered-A GEMM, direct L2-hot global B (no LDS, no barrier) ----------------
__global__ __launch_bounds__(256) void k_chem1(
    const int* __restrict__ edges, const float* __restrict__ b1)
{
    int tid = threadIdx.x;
    int lane = tid & 63, q = lane >> 4, ln = lane & 15, w = tid >> 6;
    int base = blockIdx.x * 2;
    int nt2 = (base + 1 < NTILE) ? 2 : 1;
    for (int t2 = 0; t2 < nt2; t2++) {
        int m0 = (base + t2) * 64 + w * 16;
        int e = m0 + ln;
        int r_ = edges[e], c_ = edges[EE + e];
        f32x4 acc[4];
#pragma unroll
        for (int t = 0; t < 4; t++) acc[t] = (f32x4){0.f, 0.f, 0.f, 0.f};
#pragma unroll
        for (int k0 = 0; k0 < 9; k0++) {
            int k = k0 * 32 + q * 8;
            const u16* p = nullptr;
            if (k < 64)       p = g_hb  + (size_t)r_ * 64 + k;
            else if (k < 128) p = g_hb  + (size_t)c_ * 64 + (k - 64);
            else if (k < 192) p = g_nab + (size_t)r_ * 64 + (k - 128);
            else if (k < 256) p = g_nab + (size_t)c_ * 64 + (k - 192);
            else if (k < 272) p = g_eab + (size_t)e * 16 + (k - 256);
            s16x8 af = p ? *(const s16x8*)p : (s16x8){0, 0, 0, 0, 0, 0, 0, 0};
#pragma unroll
            for (int t = 0; t < 4; t++) {
                s16x8 bf = *(const s16x8*)(&g_w1t[(t * 16 + ln) * 296 + k0 * 32 + q * 8]);
                acc[t] = __builtin_amdgcn_mfma_f32_16x16x32_bf16(af, bf, acc[t], 0, 0, 0);
            }
        }
#pragma unroll
        for (int t = 0; t < 4; t++) {
            float bv = b1[t * 16 + ln];
#pragma unroll
            for (int r = 0; r < 4; r++)
                g_t1[(size_t)(m0 + q * 4 + r) * 64 + t * 16 + ln] = f2bu(siluf(acc[t][r] + bv));
        }
    }
}

// ---------------- MegaAB: direct L2-hot global weights (no weight staging), 1 tile/block ----------------
__global__ __launch_bounds__(256) void k_megaAB(
    const float* __restrict__ chb2,
    const float* __restrict__ pW1, const float* __restrict__ pb1,
    const float* __restrict__ posb2,
    const float* __restrict__ shb,
    const float* __restrict__ attW, const float* __restrict__ attb,
    const float* __restrict__ Wb,
    const float* __restrict__ ub1, const float* __restrict__ uW2, const float* __restrict__ ub2,
    const float* __restrict__ xb1, const float* __restrict__ xW2, const float* __restrict__ xb2,
    const float* __restrict__ nb1, const float* __restrict__ nW2, const float* __restrict__ nb2,
    const int* __restrict__ edges, const float* __restrict__ nvecs)
{
    __shared__ u16 T[4][16 * 72];
    __shared__ float sWB[256], sATT[64], sPW1[128], sPB1[64];
    int tid = threadIdx.x;
    sWB[tid] = Wb[tid];
    if (tid < 128) sPW1[tid] = pW1[tid];
    if (tid < 64) { sATT[tid] = attW[tid]; sPB1[tid] = pb1[tid]; }
    __syncthreads();
    int lane = tid & 63, q = lane >> 4, ln = lane & 15, w = tid >> 6;
    int m0 = blockIdx.x * 64 + w * 16;
    const u16* wP = g_wmA[0];
    const u16* wC = g_wmA[1];
    const u16* wS = g_wmA[2];
    const u16* wU = g_wmA[3];
    const u16* wX = g_wmA[4];
    const u16* wN = g_wmA[5];
    float np_ = g_nr[m0 + ln], rad_ = g_rad[m0 + ln];
    s16x8 p1f0, p1f1;
#pragma unroll
    for (int j = 0; j < 8; j++) {
        int k = q * 8 + j;
        p1f0[j] = (short)f2bu(siluf(sPB1[k] + np_ * sPW1[k] + rad_ * sPW1[64 + k]));
        k += 32;
        p1f1[j] = (short)f2bu(siluf(sPB1[k] + np_ * sPW1[k] + rad_ * sPW1[64 + k]));
    }
    f32x4 pacc[4];
#pragma unroll
    for (int t = 0; t < 4; t++) {
        f32x4 a = (f32x4){0,0,0,0};
        a = __builtin_amdgcn_mfma_f32_16x16x32_bf16(p1f0, *(const s16x8*)(&wP[(t * 16 + ln) * 72 + q * 8]), a, 0, 0, 0);
        a = __builtin_amdgcn_mfma_f32_16x16x32_bf16(p1f1, *(const s16x8*)(&wP[(t * 16 + ln) * 72 + 32 + q * 8]), a, 0, 0, 0);
        pacc[t] = a;
    }
    float posD[4][4];
#pragma unroll
    for (int t = 0; t < 4; t++) {
        float pb = posb2[t * 16 + ln];
#pragma unroll
        for (int r = 0; r < 4; r++) posD[t][r] = siluf(pacc[t][r] + pb);
    }
    f32x4 cacc[4];
#pragma unroll
    for (int t = 0; t < 4; t++) cacc[t] = (f32x4){0,0,0,0};
    {
        const u16* ar = g_t1 + (size_t)(m0 + ln) * 64;
#pragma unroll
        for (int k0 = 0; k0 < 2; k0++) {
            s16x8 af = *(const s16x8*)(ar + k0 * 32 + q * 8);
#pragma unroll
            for (int t = 0; t < 4; t++) {
                s16x8 bf = *(const s16x8*)(&wC[(t * 16 + ln) * 72 + k0 * 32 + q * 8]);
                cacc[t] = __builtin_amdgcn_mfma_f32_16x16x32_bf16(af, bf, cacc[t], 0, 0, 0);
            }
        }
    }
#pragma unroll
    for (int t = 0; t < 4; t++) {
        float cb = chb2[t * 16 + ln];
#pragma unroll
        for (int r = 0; r < 4; r++)
            T[w][(q * 4 + r) * 72 + t * 16 + ln] = f2bu(siluf(cacc[t][r] + cb));
    }
    asm volatile("s_waitcnt lgkmcnt(0)" ::: "memory");
    s16x8 ca0 = *(const s16x8*)(&T[w][ln * 72 + q * 8]);
    s16x8 ca1 = *(const s16x8*)(&T[w][ln * 72 + 32 + q * 8]);
    f32x4 sacc[4];
#pragma unroll
    for (int t = 0; t < 4; t++) {
        f32x4 a = (f32x4){0,0,0,0};
        a = __builtin_amdgcn_mfma_f32_16x16x32_bf16(ca0, *(const s16x8*)(&wS[(t * 16 + ln) * 72 + q * 8]), a, 0, 0, 0);
        a = __builtin_amdgcn_mfma_f32_16x16x32_bf16(ca1, *(const s16x8*)(&wS[(t * 16 + ln) * 72 + 32 + q * 8]), a, 0, 0, 0);
        sacc[t] = a;
    }
    float zv[4][4];
    float part4[4] = {0.f, 0.f, 0.f, 0.f};
#pragma unroll
    for (int t = 0; t < 4; t++) {
        float sb = shb[t * 16 + ln];
        float aw = sATT[t * 16 + ln];
#pragma unroll
        for (int r = 0; r < 4; r++) {
            float o = siluf(sacc[t][r] + sb) * posD[t][r];
            zv[t][r] = o;
            part4[r] += o * aw;
        }
    }
    float ab = attb[0];
#pragma unroll
    for (int r = 0; r < 4; r++) {
        float sg = sigmf(quadSum(part4[r]) + ab);
        size_t row = m0 + q * 4 + r;
#pragma unroll
        for (int t = 0; t < 4; t++) {
            float z = zv[t][r] * sg;
            zv[t][r] = z;
            g_z16[row * 64 + t * 16 + ln] = f2bu(z);
        }
    }
#pragma unroll
    for (int hd = 0; hd < 4; hd++) {
#pragma unroll
        for (int r = 0; r < 4; r++) {
            float p = 0.f;
#pragma unroll
            for (int t = 0; t < 4; t++) p += zv[t][r] * sWB[hd * 64 + t * 16 + ln];
            p = quadSum(p);
            if (ln == hd) g_b4[(size_t)(m0 + q * 4 + r) * 4 + hd] = p;
        }
    }
#pragma unroll
    for (int t = 0; t < 4; t++)
#pragma unroll
        for (int r = 0; r < 4; r++)
            T[w][(q * 4 + r) * 72 + t * 16 + ln] = f2bu(posD[t][r]);
    asm volatile("s_waitcnt lgkmcnt(0)" ::: "memory");
    s16x8 pa0 = *(const s16x8*)(&T[w][ln * 72 + q * 8]);
    s16x8 pa1 = *(const s16x8*)(&T[w][ln * 72 + 32 + q * 8]);
    f32x4 uacc[4];
#pragma unroll
    for (int t = 0; t < 4; t++) {
        f32x4 a = (f32x4){0,0,0,0};
        a = __builtin_amdgcn_mfma_f32_16x16x32_bf16(ca0, *(const s16x8*)(&wU[(t * 16 + ln) * 72 + q * 8]), a, 0, 0, 0);
        a = __builtin_amdgcn_mfma_f32_16x16x32_bf16(ca1, *(const s16x8*)(&wU[(t * 16 + ln) * 72 + 32 + q * 8]), a, 0, 0, 0);
        uacc[t] = a;
    }
    float up[4] = {0.f, 0.f, 0.f, 0.f};
#pragma unroll
    for (int t = 0; t < 4; t++) {
        float ub = ub1[t * 16 + ln];
        float w2 = uW2[t * 16 + ln];
#pragma unroll
        for (int r = 0; r < 4; r++) up[r] += siluf(uacc[t][r] + ub) * w2;
    }
    float ub2v = ub2[0];
    float pu[4];
#pragma unroll
    for (int r = 0; r < 4; r++) pu[r] = quadSum(up[r]) + ub2v;
    f32x4 xacc[4], nacc[4];
#pragma unroll
    for (int t = 0; t < 4; t++) {
        f32x4 a = (f32x4){0,0,0,0}, b = (f32x4){0,0,0,0};
        a = __builtin_amdgcn_mfma_f32_16x16x32_bf16(pa0, *(const s16x8*)(&wX[(t * 16 + ln) * 72 + q * 8]), a, 0, 0, 0);
        a = __builtin_amdgcn_mfma_f32_16x16x32_bf16(pa1, *(const s16x8*)(&wX[(t * 16 + ln) * 72 + 32 + q * 8]), a, 0, 0, 0);
        b = __builtin_amdgcn_mfma_f32_16x16x32_bf16(pa0, *(const s16x8*)(&wN[(t * 16 + ln) * 72 + q * 8]), b, 0, 0, 0);
        b = __builtin_amdgcn_mfma_f32_16x16x32_bf16(pa1, *(const s16x8*)(&wN[(t * 16 + ln) * 72 + 32 + q * 8]), b, 0, 0, 0);
        xacc[t] = a; nacc[t] = b;
    }
    float xp[4] = {0,0,0,0}, npv[4] = {0,0,0,0};
#pragma unroll
    for (int t = 0; t < 4; t++) {
        float xb = xb1[t * 16 + ln], nb = nb1[t * 16 + ln];
        float xw = xW2[t * 16 + ln], nw = nW2[t * 16 + ln];
#pragma unroll
        for (int r = 0; r < 4; r++) {
            xp[r] += siluf(xacc[t][r] + xb) * xw;
            npv[r] += siluf(nacc[t][r] + nb) * nw;
        }
    }
    float xb2v = xb2[0], nb2v = nb2[0];
#pragma unroll
    for (int r = 0; r < 4; r++) {
        float phix = quadSum(xp[r]) + xb2v;
        float phin = quadSum(npv[r]) + nb2v;
        int row = m0 + q * 4 + r;
        float tx = pu[r] * phix, tn = pu[r] * phin;
        int cc = edges[EE + row];
        if (ln < 3) {
            g_xe[row * 3 + ln] = g_cdl[row * 3 + ln] * tx;
            g_ne[row * 3 + ln] = nvecs[cc * 3 + ln] * tn;
        }
    }
}

// ---------------- attention: 1-wave blocks, fused qp + 2-deep pipeline (frozen: at gather wall) ----------------
struct STG { s16x8 za0, za1, qb0, qb1; f32x4 bv; };

__global__ __launch_bounds__(64) void k_attn2(const int* __restrict__ klist)
{
    __shared__ u16 sQP[16][256];           // qp tile: [edge j][hd*64+d]
    __shared__ u16 zT[16 * 72];
    __shared__ __align__(16) float sA[4][16];
    int lane = threadIdx.x & 63, q = lane >> 4, ln = lane & 15;
    int m0 = blockIdx.x * 16;              // wave owns edges m0..m0+15
    u16* zw = zT;

    // ---- phase 1: qp = z[own] @ M for the 16 own edges (B-frags from global g_Mt, L2-hot) ----
    {
        const u16* zr = g_z16 + (size_t)(m0 + ln) * 64;
        s16x8 af0 = *(const s16x8*)(zr + q * 8);
        s16x8 af1 = *(const s16x8*)(zr + 32 + q * 8);
#pragma unroll
        for (int hd = 0; hd < 4; hd++) {
            f32x4 aM[4];
#pragma unroll
            for (int t = 0; t < 4; t++) {
                f32x4 a = (f32x4){0,0,0,0};
                a = __builtin_amdgcn_mfma_f32_16x16x32_bf16(af0, *(const s16x8*)(&g_Mt[hd][(t * 16 + ln) * 72 + q * 8]), a, 0, 0, 0);
                a = __builtin_amdgcn_mfma_f32_16x16x32_bf16(af1, *(const s16x8*)(&g_Mt[hd][(t * 16 + ln) * 72 + 32 + q * 8]), a, 0, 0, 0);
                aM[t] = a;
            }
#pragma unroll
            for (int t = 0; t < 4; t++)
#pragma unroll
                for (int r = 0; r < 4; r++)
                    sQP[q * 4 + r][hd * 64 + t * 16 + ln] = f2bu(aM[t][r]);
        }
    }
    asm volatile("s_waitcnt lgkmcnt(0)" ::: "memory");

    // ---- phase 2: attention over own 16 edges, 2-deep-ahead pipeline ----
    auto ldkl = [&](int j) -> int {
        return (lane < 32) ? klist[(size_t)(m0 + j) * 32 + lane] : -1;
    };
    auto stage = [&](int kv, int j) -> STG {
        STG s;
        s.za0 = (s16x8){0,0,0,0,0,0,0,0}; s.za1 = (s16x8){0,0,0,0,0,0,0,0};
        s.qb0 = (s16x8){0,0,0,0,0,0,0,0}; s.qb1 = (s16x8){0,0,0,0,0,0,0,0};
        int ij = __shfl(kv, ln);
        if (ij >= 0) {
            const u16* zr = g_z16 + (size_t)ij * 64;
            s.za0 = *(const s16x8*)(zr + q * 8);
            s.za1 = *(const s16x8*)(zr + 32 + q * 8);
        }
        if (ln < 4) {
            s.qb0 = *(const s16x8*)(&sQP[j][ln * 64 + q * 8]);
            s.qb1 = *(const s16x8*)(&sQP[j][ln * 64 + 32 + q * 8]);
        }
        s.bv = (f32x4){0.f, 0.f, 0.f, 0.f};
#pragma unroll
        for (int r = 0; r < 4; r++) {
            int ijj = __shfl(kv, q * 4 + r);
            int jj = __shfl(kv, 16 + q * 4 + r);
            s.bv[r] = (ijj >= 0 && ln < 4) ? g_b4[(size_t)jj * 4 + ln] : 0.f;
        }
        return s;
    };

    int kvA = ldkl(0), kvB = ldkl(1), kvC = ldkl(2);
    STG s0 = stage(kvA, 0);
    STG s1 = stage(kvB, 1);
#pragma unroll 1
    for (int j = 0; j < 16; j++) {
        int kvD = (j + 3 < 16) ? ldkl(j + 3) : -1;
        STG s2;
        if (j + 2 < 16) s2 = stage(kvC, j + 2);
        else {
            s2.za0 = (s16x8){0,0,0,0,0,0,0,0}; s2.za1 = s2.za0;
            s2.qb0 = s2.za0; s2.qb1 = s2.za0;
            s2.bv = (f32x4){0.f, 0.f, 0.f, 0.f};
        }
        // scores (validity folded: za=0 & bv=0 for masked slots -> s=0)
        f32x4 sc = (f32x4){0.f, 0.f, 0.f, 0.f};
        sc = __builtin_amdgcn_mfma_f32_16x16x32_bf16(s0.za0, s0.qb0, sc, 0, 0, 0);
        sc = __builtin_amdgcn_mfma_f32_16x16x32_bf16(s0.za1, s0.qb1, sc, 0, 0, 0);
        *(s16x8*)(&zw[ln * 72 + q * 8]) = s0.za0;
        *(s16x8*)(&zw[ln * 72 + 32 + q * 8]) = s0.za1;
        float s[4];
#pragma unroll
        for (int r = 0; r < 4; r++) s[r] = 0.125f * sc[r] + s0.bv[r];
        float mx = fmaxf(fmaxf(s[0], s[1]), fmaxf(s[2], s[3]));
        mx = fmaxf(mx, __shfl_xor(mx, 16));
        mx = fmaxf(mx, __shfl_xor(mx, 32));
        float ex[4], ps = 0.f;
#pragma unroll
        for (int r = 0; r < 4; r++) { ex[r] = __expf(s[r] - mx); ps += ex[r]; }
        ps += __shfl_xor(ps, 16);
        ps += __shfl_xor(ps, 32);
        float inv = 1.f / ps;
        if (ln < 4)
            *(f32x4*)&sA[ln][q * 4] = (f32x4){ex[0] * inv, ex[1] * inv, ex[2] * inv, ex[3] * inv};
        asm volatile("s_waitcnt lgkmcnt(0)" ::: "memory");
        float t0 = 0.f, t1 = 0.f, t2 = 0.f, t3 = 0.f;
#pragma unroll
        for (int j4 = 0; j4 < 4; j4++) {
            f32x4 a0 = *(const f32x4*)&sA[0][j4 * 4];
            f32x4 a1 = *(const f32x4*)&sA[1][j4 * 4];
            f32x4 a2 = *(const f32x4*)&sA[2][j4 * 4];
            f32x4 a3 = *(const f32x4*)&sA[3][j4 * 4];
#pragma unroll
            for (int r = 0; r < 4; r++) {
                float zz = us2f(zw[(j4 * 4 + r) * 72 + lane]);
                t0 += a0[r] * zz; t1 += a1[r] * zz; t2 += a2[r] * zz; t3 += a3[r] * zz;
            }
        }
        size_t ob = (size_t)(m0 + j) * 64 + lane;
        g_t4[0][ob] = f2bu(t0);
        g_t4[1][ob] = f2bu(t1);
        g_t4[2][ob] = f2bu(t2);
        g_t4[3][ob] = f2bu(t3);
        kvA = kvB; kvB = kvC; kvC = kvD;
        s0 = s1; s1 = s2;
    }
}

// ---------------- fused heads: direct L2-hot global B-operands (no LDS weight staging, no barriers) ----------------
__global__ __launch_bounds__(256) void k_us(
    const float* __restrict__ bg, const int* __restrict__ edges)
{
    __shared__ u16 sU[4][16 * 72];
    int tid = threadIdx.x;
    int lane = tid & 63, q = lane >> 4, ln = lane & 15, w = tid >> 6;
    int m0 = blockIdx.x * 64 + w * 16;
    const u16* zr = g_z16 + (size_t)(m0 + ln) * 64;
    s16x8 za[2];
    za[0] = *(const s16x8*)(zr + q * 8);
    za[1] = *(const s16x8*)(zr + 32 + q * 8);
    f32x4 macc[4];
#pragma unroll
    for (int t = 0; t < 4; t++) macc[t] = (f32x4){0,0,0,0};
    for (int hd = 0; hd < 4; hd++) {
        const u16* wV = g_wpre[hd * 3 + 0];
        const u16* wO = g_wpre[hd * 3 + 1];
        const u16* wG = g_wpre[hd * 3 + 2];
        f32x4 vacc[4], gacc[4];
#pragma unroll
        for (int t = 0; t < 4; t++) { vacc[t] = (f32x4){0,0,0,0}; gacc[t] = (f32x4){0,0,0,0}; }
        const u16* ar = &g_t4[hd][(size_t)(m0 + ln) * 64];
#pragma unroll
        for (int k0 = 0; k0 < 2; k0++) {
            s16x8 af = *(const s16x8*)(ar + k0 * 32 + q * 8);
#pragma unroll
            for (int t = 0; t < 4; t++) {
                vacc[t] = __builtin_amdgcn_mfma_f32_16x16x32_bf16(
                    af, *(const s16x8*)(&wV[(t * 16 + ln) * 72 + k0 * 32 + q * 8]), vacc[t], 0, 0, 0);
                gacc[t] = __builtin_amdgcn_mfma_f32_16x16x32_bf16(
                    za[k0], *(const s16x8*)(&wG[(t * 16 + ln) * 72 + k0 * 32 + q * 8]), gacc[t], 0, 0, 0);
            }
        }
#pragma unroll
        for (int t = 0; t < 4; t++) {
            float bb = bg[hd * 64 + t * 16 + ln];
#pragma unroll
            for (int r = 0; r < 4; r++) {
                float u = vacc[t][r] * sigmf(gacc[t][r] + bb);
                sU[w][(q * 4 + r) * 72 + t * 16 + ln] = f2bu(u);
            }
        }
        asm volatile("s_waitcnt lgkmcnt(0)" ::: "memory");
#pragma unroll
        for (int k0 = 0; k0 < 2; k0++) {
            s16x8 af = *(const s16x8*)(&sU[w][ln * 72 + k0 * 32 + q * 8]);
#pragma unroll
            for (int t = 0; t < 4; t++) {
                macc[t] = __builtin_amdgcn_mfma_f32_16x16x32_bf16(
                    af, *(const s16x8*)(&wO[(t * 16 + ln) * 72 + k0 * 32 + q * 8]), macc[t], 0, 0, 0);
            }
        }
        asm volatile("s_waitcnt lgkmcnt(0)" ::: "memory");
    }
#pragma unroll
    for (int r = 0; r < 4; r++) {
        size_t dst = (size_t)(m0 + q * 4 + r) * 64;
#pragma unroll
        for (int t = 0; t < 4; t++) g_me[dst + t * 16 + ln] = macc[t][r];
    }
}

// ---------------- CSR aggregation: one wave per node; m mean + coord/nvec finalize ----------------
__global__ __launch_bounds__(256) void k_agg(
    const float* __restrict__ coord, const float* __restrict__ nvecs,
    const float* __restrict__ icoord, const float* __restrict__ invecs,
    const float* __restrict__ ob, float* __restrict__ out)
{
    int tid = threadIdx.x;
    int lane = tid & 63;
    int n = blockIdx.x * 4 + (tid >> 6);
    if (n >= NN) return;
    int r0 = g_roff[n], r1 = g_roff[n + 1];
    int deg = r1 - r0;
    float msA = 0.f, msB = 0.f, msC = 0.f, msD = 0.f;
    float xs0 = 0.f, xs1 = 0.f, xs2 = 0.f, ns0 = 0.f, ns1 = 0.f, ns2 = 0.f;
    for (int base = r0; base < r1; base += 64) {
        int idx = base + lane;
        int e_l = (idx < r1) ? g_eid[idx] : -1;
        int cnt = min(64, r1 - base);
        int j = 0;
        for (; j + 3 < cnt; j += 4) {
            int ea = __shfl(e_l, j), eb = __shfl(e_l, j + 1);
            int ec = __shfl(e_l, j + 2), ed = __shfl(e_l, j + 3);
            msA += g_me[(size_t)ea * 64 + lane];
            msB += g_me[(size_t)eb * 64 + lane];
            msC += g_me[(size_t)ec * 64 + lane];
            msD += g_me[(size_t)ed * 64 + lane];
        }
        for (; j < cnt; j++) {
            int ea = __shfl(e_l, j);
            msA += g_me[(size_t)ea * 64 + lane];
        }
        if (e_l >= 0) {
            xs0 += g_xe[e_l * 3 + 0]; xs1 += g_xe[e_l * 3 + 1]; xs2 += g_xe[e_l * 3 + 2];
            ns0 += g_ne[e_l * 3 + 0]; ns1 += g_ne[e_l * 3 + 1]; ns2 += g_ne[e_l * 3 + 2];
        }
    }
    xs0 = waveSum(xs0); xs1 = waveSum(xs1); xs2 = waveSum(xs2);
    ns0 = waveSum(ns0); ns1 = waveSum(ns1); ns2 = waveSum(ns2);
    float rinv = 1.f / fmaxf((float)deg, 1.f);
    float obv = (deg > 0) ? ob[lane] : 0.f;
    g_mavg[(size_t)n * 64 + lane] = (msA + msB + msC + msD) * rinv + obv;
    if (lane == 0) {
        size_t coff = (size_t)NN * 64;
        size_t noff = coff + (size_t)NN * 3;
        float xs[3] = {xs0, xs1, xs2}, ns[3] = {ns0, ns1, ns2};
        float nl[3];
#pragma unroll
        for (int c = 0; c < 3; c++) {
            out[coff + n * 3 + c] = 0.2f * icoord[n * 3 + c] + 0.8f * coord[n * 3 + c] + xs[c] * rinv;
            nl[c] = 0.2f * invecs[n * 3 + c] + 0.8f * nvecs[n * 3 + c] + ns[c] * rinv;
        }
        float nn2 = sqrtf(nl[0] * nl[0] + nl[1] * nl[1] + nl[2] * nl[2]) + 1e-8f;
#pragma unroll
        for (int c = 0; c < 3; c++) out[noff + n * 3 + c] = nl[c] / nn2;
    }
}

// ---------------- node finalize: MFMA MLP over [h|na|m_agg] ----------------
__global__ __launch_bounds__(256) void k_node(
    const float* __restrict__ h, const float* __restrict__ na,
    const float* __restrict__ W1, const float* __restrict__ b1,
    const float* __restrict__ W2, const float* __restrict__ b2,
    float* __restrict__ out)
{
    __shared__ u16 sW1T[64 * 200];
    __shared__ u16 sW2T[64 * 72];
    __shared__ u16 sA[64 * 200];
    __shared__ u16 sT[64 * 72];
    __shared__ float sb2v[64];
    int tid = threadIdx.x;
    int m0 = blockIdx.x * 64;
    for (int i = tid; i < 64 * 192; i += 256) {
        int n = i / 192, k = i - n * 192;
        sW1T[n * 200 + k] = f2bu(W1[k * 64 + n]);
    }
    for (int i = tid; i < 4096; i += 256) {
        int k = i >> 6, n = i & 63;
        sW2T[n * 72 + k] = f2bu(W2[i]);
    }
    if (tid < 64) sb2v[tid] = b2[tid];
    for (int i = tid; i < 4096; i += 256) {
        int row = i >> 6, d = i & 63;
        int n = m0 + row; if (n >= NN) n = NN - 1;
        sA[row * 200 + d] = f2bu(h[(size_t)n * 64 + d]);
        sA[row * 200 + 64 + d] = f2bu(na[(size_t)n * 64 + d]);
        sA[row * 200 + 128 + d] = f2bu(g_mavg[(size_t)n * 64 + d]);
    }
    __syncthreads();
    int lane = tid & 63, q = lane >> 4, ln = lane & 15, w = tid >> 6;
    f32x4 acc[4];
#pragma unroll
    for (int t = 0; t < 4; t++) acc[t] = (f32x4){0.f, 0.f, 0.f, 0.f};
#pragma unroll
    for (int k0 = 0; k0 < 6; k0++) {
        s16x8 af = *(const s16x8*)(&sA[(w * 16 + ln) * 200 + k0 * 32 + q * 8]);
#pragma unroll
        for (int t = 0; t < 4; t++) {
            s16x8 bf = *(const s16x8*)(&sW1T[(t * 16 + ln) * 200 + k0 * 32 + q * 8]);
            acc[t] = __builtin_amdgcn_mfma_f32_16x16x32_bf16(af, bf, acc[t], 0, 0, 0);
        }
    }
#pragma unroll
    for (int t = 0; t < 4; t++) {
        float bv = b1[t * 16 + ln];
#pragma unroll
        for (int r = 0; r < 4; r++)
            sT[(w * 16 + q * 4 + r) * 72 + t * 16 + ln] = f2bu(siluf(acc[t][r] + bv));
    }
    asm volatile("s_waitcnt lgkmcnt(0)" ::: "memory");
    f32x4 acc2[4];
#pragma unroll
    for (int t = 0; t < 4; t++) acc2[t] = (f32x4){0.f, 0.f, 0.f, 0.f};
#pragma unroll
    for (int k0 = 0; k0 < 2; k0++) {
        s16x8 af = *(const s16x8*)(&sT[(w * 16 + ln) * 72 + k0 * 32 + q * 8]);
#pragma unroll
        for (int t = 0; t < 4; t++) {
            s16x8 bf = *(const s16x8*)(&sW2T[(t * 16 + ln) * 72 + k0 * 32 + q * 8]);
            acc2[t] = __builtin_amdgcn_mfma_f32_16x16x32_bf16(af, bf, acc2[t], 0, 0, 0);
        }
    }
#pragma unroll
    for (int r = 0; r < 4; r++) {
        int n = m0 + w * 16 + q * 4 + r;
        if (n < NN) {
#pragma unroll
            for (int t = 0; t < 4; t++) {
                int d = t * 16 + ln;
                out[(size_t)n * 64 + d] = 0.2f * h[(size_t)n * 64 + d] + 0.8f * (acc2[t][r] + sb2v[d]);
            }
        }
    }
}

extern "C" void kernel_launch(void* const* d_in, const int* in_sizes, int n_in,
                              void* d_out, int out_size, void* d_ws, size_t ws_size,
                              hipStream_t stream)
{
    const int* edges = (const int*)d_in[43];
    const int* klist = (const int*)d_in[44];
    auto F = [&](int i) { return (const float*)d_in[i]; };

    k_zero<<<40, 256, 0, stream>>>();
    k_prep<<<512, 256, 0, stream>>>(F(19), F(20), F(0), F(4), F(3), F(1), F(2),
                                    F(21), F(23), F(25),
                                    F(13), F(9), F(15), F(27), F(31), F(35), F(7),
                                    edges);
    k_scan<<<1, 256, 0, stream>>>();
    k_fill<<<782, 256, 0, stream>>>(edges);
    k_chem1<<<1563, 256, 0, stream>>>(edges, F(8));
    k_megaAB<<<3125, 256, 0, stream>>>(F(10), F(11), F(12), F(14),
                                       F(16), F(17), F(18), F(22),
                                       F(28), F(29), F(30),
                                       F(32), F(33), F(34),
                                       F(36), F(37), F(38),
                                       edges, F(2));
    k_attn2<<<12500, 64, 0, stream>>>(klist);
    k_us<<<3125, 256, 0, stream>>>(F(24), edges);
    k_agg<<<2500, 256, 0, stream>>>(F(1), F(2), F(5), F(6), F(26), (float*)d_out);
    k_node<<<157, 256, 0, stream>>>(F(0), F(4), F(39), F(40), F(41), F(42), (float*)d_out);
}

// Round 14
// 645.464 us; speedup vs baseline: 1.0126x; 1.0126x over previous
//
#include <hip/hip_runtime.h>

typedef unsigned short u16;
typedef unsigned int u32;
typedef __attribute__((ext_vector_type(8))) short s16x8;
typedef __attribute__((ext_vector_type(4))) float f32x4;

#define NN 10000
#define EE 200000
#define ES ((size_t)EE * 64)
#define NTILE 3125

#define DEVI __device__ __forceinline__

DEVI float us2f(u16 u) {
    union { u32 i; float f; } v; v.i = ((u32)u) << 16; return v.f;
}
DEVI u16 f2bu(float f) {
    union { float f; u32 i; } v; v.f = f;
    u32 x = v.i;
    return (u16)((x + 0x7fffu + ((x >> 16) & 1u)) >> 16);
}
DEVI float siluf(float x) { return x / (1.f + __expf(-x)); }
DEVI float sigmf(float x) { return 1.f / (1.f + __expf(-x)); }
DEVI float waveSum(float v) {
#pragma unroll
    for (int o = 32; o; o >>= 1) v += __shfl_xor(v, o);
    return v;
}
DEVI float quadSum(float v) {
#pragma unroll
    for (int o = 1; o < 16; o <<= 1) v += __shfl_xor(v, o);
    return v;
}

// ---- module-owned scratch ----
__device__ u16 g_hb[(size_t)NN * 64];
__device__ u16 g_nab[(size_t)NN * 64];
__device__ u16 g_eab[(size_t)EE * 16];
__device__ u16 g_t1[ES];
__device__ u16 g_z16[ES];
__device__ u16 g_t4[4][ES];
__device__ __align__(16) u16 g_Mt[4][4608];     // [hd][n*72+k] bf16 pre-transposed Wq@Wk^T
__device__ __align__(16) u16 g_wpre[12][4608];  // [hd*3+{V,O,G}][n*72+k] bf16 pre-transposed
__device__ __align__(16) u16 g_wmA[6][4608];    // megaAB: posW2,chW2,shW,uW1,xW1,nW1 pre-transposed
__device__ __align__(16) u16 g_w1t[64 * 296];   // chem1 B^T (bf16, padded K to 296)
__device__ float g_b4[(size_t)EE * 4];
__device__ float g_nr[EE];
__device__ float g_rad[EE];
__device__ float g_cdl[EE * 3];
// CSR aggregation
__device__ int g_degi[NN];
__device__ int g_fill[NN];
__device__ int g_roff[NN + 1];
__device__ int g_eid[EE];
__device__ float g_me[(size_t)EE * 64];   // per-edge m rows (fp32)
__device__ float g_xe[EE * 3];
__device__ float g_ne[EE * 3];
__device__ float g_mavg[(size_t)NN * 64];

// ---------------- zero CSR counters ----------------
__global__ __launch_bounds__(256) void k_zero()
{
    int t = blockIdx.x * 256 + threadIdx.x;
    if (t < NN) { g_degi[t] = 0; g_fill[t] = 0; }
}

// ---------------- prep: Mt, weight pre-convert (heads + megaAB + chem1), bf16, geometry, deg ----------------
__global__ __launch_bounds__(256) void k_prep(
    const float* __restrict__ Wq, const float* __restrict__ Wk,
    const float* __restrict__ h, const float* __restrict__ na, const float* __restrict__ ea,
    const float* __restrict__ coord, const float* __restrict__ nvecs,
    const float* __restrict__ Wv, const float* __restrict__ Wg, const float* __restrict__ oW,
    const float* __restrict__ posW2, const float* __restrict__ chW2, const float* __restrict__ shW,
    const float* __restrict__ uW1, const float* __restrict__ xW1, const float* __restrict__ nW1,
    const float* __restrict__ chemW1,
    const int* __restrict__ edges)
{
    int t = blockIdx.x * 256 + threadIdx.x;
    if (t < 16384) {
        int hd = t >> 12, rem = t & 4095, k = rem >> 6, n = rem & 63;
        const float* wq = Wq + (size_t)hd * 4096 + k * 64;
        const float* wk = Wk + (size_t)hd * 4096 + n * 64;
        float acc = 0.f;
        for (int d = 0; d < 64; d++) acc += wq[d] * wk[d];
        int off = n * 72 + k;
        g_Mt[hd][off] = f2bu(acc);
        g_wpre[hd * 3 + 0][off] = f2bu(Wv[t]);
        g_wpre[hd * 3 + 1][off] = f2bu(oW[t]);
        g_wpre[hd * 3 + 2][off] = f2bu(Wg[t]);
    }
    int nt = gridDim.x * 256;
    // megaAB weights: pre-transposed bf16 [n*72+k]
    for (int i = t; i < 6 * 4096; i += nt) {
        int a = i >> 12, rem = i & 4095, k = rem >> 6, n = rem & 63;
        const float* s;
        if (a == 0) s = posW2;
        else if (a == 1) s = chW2;
        else if (a == 2) s = shW;
        else if (a == 3) s = uW1;
        else if (a == 4) s = xW1;
        else s = nW1;
        g_wmA[a][n * 72 + k] = f2bu(s[rem]);
    }
    // chem1 B^T, K padded to 296
    for (int i = t; i < 64 * 296; i += nt) {
        int n = i / 296, k = i - n * 296;
        g_w1t[i] = (k < 272) ? f2bu(chemW1[k * 64 + n]) : (u16)0;
    }
    for (int i = t; i < NN * 64; i += nt) { g_hb[i] = f2bu(h[i]); g_nab[i] = f2bu(na[i]); }
    for (size_t i = t; i < (size_t)EE * 16; i += nt) g_eab[i] = f2bu(ea[i]);
    for (int e = t; e < EE; e += nt) {
        int r = edges[e], c = edges[EE + e];
        atomicAdd(&g_degi[r], 1);
        float d0 = coord[r * 3 + 0] - coord[c * 3 + 0];
        float d1 = coord[r * 3 + 1] - coord[c * 3 + 1];
        float d2 = coord[r * 3 + 2] - coord[c * 3 + 2];
        float radial = d0 * d0 + d1 * d1 + d2 * d2;
        float np = nvecs[r * 3 + 0] * nvecs[c * 3 + 0]
                 + nvecs[r * 3 + 1] * nvecs[c * 3 + 1]
                 + nvecs[r * 3 + 2] * nvecs[c * 3 + 2];
        float rinv = 1.f / (sqrtf(radial) + 1e-8f);
        g_cdl[e * 3 + 0] = d0 * rinv;
        g_cdl[e * 3 + 1] = d1 * rinv;
        g_cdl[e * 3 + 2] = d2 * rinv;
        g_nr[e] = np;
        g_rad[e] = radial;
    }
}

// ---------------- exclusive scan of degrees (1 block) ----------------
__global__ __launch_bounds__(256) void k_scan()
{
    __shared__ int ls[256];
    int tid = threadIdx.x;
    int basei = tid * 40;
    int loc[40];
    int cnt = 0;
#pragma unroll
    for (int i = 0; i < 40; i++) {
        int idx = basei + i;
        int v = (idx < NN) ? g_degi[idx] : 0;
        loc[i] = cnt; cnt += v;
    }
    ls[tid] = cnt;
    __syncthreads();
    int off = 0;
    for (int i = 0; i < tid; i++) off += ls[i];
#pragma unroll
    for (int i = 0; i < 40; i++) {
        int idx = basei + i;
        if (idx < NN) g_roff[idx] = off + loc[i];
    }
    if (tid == 255) g_roff[NN] = off + cnt;
}

// ---------------- CSR fill ----------------
__global__ __launch_bounds__(256) void k_fill(const int* __restrict__ edges)
{
    int e = blockIdx.x * 256 + threadIdx.x;
    if (e < EE) {
        int r = edges[e];
        int slot = atomicAdd(&g_fill[r], 1);
        g_eid[g_roff[r] + slot] = e;
    }
}

// ---------------- chem layer1: gathered-A GEMM (bf16 sources), K=288, 2 tiles/block ----------------
__global__ __launch_bounds__(256) void k_chem1(
    const int* __restrict__ edges, const float* __restrict__ b1)
{
    __shared__ __align__(16) u16 sBT[64 * 296];
    int tid = threadIdx.x;
    {
        u32* d = (u32*)sBT; const u32* s = (const u32*)g_w1t;
        for (int i = tid; i < 9472; i += 256) d[i] = s[i];
    }
    __syncthreads();
    int lane = tid & 63, q = lane >> 4, ln = lane & 15, w = tid >> 6;
    int base = blockIdx.x * 2;
    int nt2 = (base + 1 < NTILE) ? 2 : 1;
    for (int t2 = 0; t2 < nt2; t2++) {
        int m0 = (base + t2) * 64 + w * 16;
        int e = m0 + ln;
        int r_ = edges[e], c_ = edges[EE + e];
        f32x4 acc[4];
#pragma unroll
        for (int t = 0; t < 4; t++) acc[t] = (f32x4){0.f, 0.f, 0.f, 0.f};
#pragma unroll
        for (int k0 = 0; k0 < 9; k0++) {
            int k = k0 * 32 + q * 8;
            const u16* p = nullptr;
            if (k < 64)       p = g_hb  + (size_t)r_ * 64 + k;
            else if (k < 128) p = g_hb  + (size_t)c_ * 64 + (k - 64);
            else if (k < 192) p = g_nab + (size_t)r_ * 64 + (k - 128);
            else if (k < 256) p = g_nab + (size_t)c_ * 64 + (k - 192);
            else if (k < 272) p = g_eab + (size_t)e * 16 + (k - 256);
            s16x8 af = p ? *(const s16x8*)p : (s16x8){0, 0, 0, 0, 0, 0, 0, 0};
#pragma unroll
            for (int t = 0; t < 4; t++) {
                s16x8 bf = *(const s16x8*)(&sBT[(t * 16 + ln) * 296 + k0 * 32 + q * 8]);
                acc[t] = __builtin_amdgcn_mfma_f32_16x16x32_bf16(af, bf, acc[t], 0, 0, 0);
            }
        }
#pragma unroll
        for (int t = 0; t < 4; t++) {
            float bv = b1[t * 16 + ln];
#pragma unroll
            for (int r = 0; r < 4; r++)
                g_t1[(size_t)(m0 + q * 4 + r) * 64 + t * 16 + ln] = f2bu(siluf(acc[t][r] + bv));
        }
    }
}

// straight u32 copy of pre-converted bf16 weights (covers full 64*72 incl. pad)
DEVI void stageP(u16* dst, const u16* src, int tid) {
    u32* d = (u32*)dst; const u32* s = (const u32*)src;
    for (int i = tid; i < 2304; i += 256) d[i] = s[i];
}

// ---------------- MegaAB: two-phase pre-converted weight staging, 1 tile/block ----------------
__global__ __launch_bounds__(256) void k_megaAB(
    const float* __restrict__ chb2,
    const float* __restrict__ pW1, const float* __restrict__ pb1,
    const float* __restrict__ posb2,
    const float* __restrict__ shb,
    const float* __restrict__ attW, const float* __restrict__ attb,
    const float* __restrict__ Wb,
    const float* __restrict__ ub1, const float* __restrict__ uW2, const float* __restrict__ ub2,
    const float* __restrict__ xb1, const float* __restrict__ xW2, const float* __restrict__ xb2,
    const float* __restrict__ nb1, const float* __restrict__ nW2, const float* __restrict__ nb2,
    const int* __restrict__ edges, const float* __restrict__ nvecs)
{
    __shared__ __align__(16) u16 sW0[64 * 72], sW1b[64 * 72], sW2b[64 * 72];
    __shared__ u16 T[4][16 * 72];
    __shared__ float sWB[256], sATT[64], sPW1[128], sPB1[64];
    int tid = threadIdx.x;
    stageP(sW0, g_wmA[0], tid); stageP(sW1b, g_wmA[1], tid); stageP(sW2b, g_wmA[2], tid);
    sWB[tid] = Wb[tid];
    if (tid < 128) sPW1[tid] = pW1[tid];
    if (tid < 64) { sATT[tid] = attW[tid]; sPB1[tid] = pb1[tid]; }
    __syncthreads();
    int lane = tid & 63, q = lane >> 4, ln = lane & 15, w = tid >> 6;
    int m0 = blockIdx.x * 64 + w * 16;
    float np_ = g_nr[m0 + ln], rad_ = g_rad[m0 + ln];
    s16x8 p1f0, p1f1;
#pragma unroll
    for (int j = 0; j < 8; j++) {
        int k = q * 8 + j;
        p1f0[j] = (short)f2bu(siluf(sPB1[k] + np_ * sPW1[k] + rad_ * sPW1[64 + k]));
        k += 32;
        p1f1[j] = (short)f2bu(siluf(sPB1[k] + np_ * sPW1[k] + rad_ * sPW1[64 + k]));
    }
    f32x4 pacc[4];
#pragma unroll
    for (int t = 0; t < 4; t++) {
        f32x4 a = (f32x4){0,0,0,0};
        a = __builtin_amdgcn_mfma_f32_16x16x32_bf16(p1f0, *(const s16x8*)(&sW0[(t * 16 + ln) * 72 + q * 8]), a, 0, 0, 0);
        a = __builtin_amdgcn_mfma_f32_16x16x32_bf16(p1f1, *(const s16x8*)(&sW0[(t * 16 + ln) * 72 + 32 + q * 8]), a, 0, 0, 0);
        pacc[t] = a;
    }
    float posD[4][4];
#pragma unroll
    for (int t = 0; t < 4; t++) {
        float pb = posb2[t * 16 + ln];
#pragma unroll
        for (int r = 0; r < 4; r++) posD[t][r] = siluf(pacc[t][r] + pb);
    }
    f32x4 cacc[4];
#pragma unroll
    for (int t = 0; t < 4; t++) cacc[t] = (f32x4){0,0,0,0};
    {
        const u16* ar = g_t1 + (size_t)(m0 + ln) * 64;
#pragma unroll
        for (int k0 = 0; k0 < 2; k0++) {
            s16x8 af = *(const s16x8*)(ar + k0 * 32 + q * 8);
#pragma unroll
            for (int t = 0; t < 4; t++) {
                s16x8 bf = *(const s16x8*)(&sW1b[(t * 16 + ln) * 72 + k0 * 32 + q * 8]);
                cacc[t] = __builtin_amdgcn_mfma_f32_16x16x32_bf16(af, bf, cacc[t], 0, 0, 0);
            }
        }
    }
#pragma unroll
    for (int t = 0; t < 4; t++) {
        float cb = chb2[t * 16 + ln];
#pragma unroll
        for (int r = 0; r < 4; r++)
            T[w][(q * 4 + r) * 72 + t * 16 + ln] = f2bu(siluf(cacc[t][r] + cb));
    }
    asm volatile("s_waitcnt lgkmcnt(0)" ::: "memory");
    s16x8 ca0 = *(const s16x8*)(&T[w][ln * 72 + q * 8]);
    s16x8 ca1 = *(const s16x8*)(&T[w][ln * 72 + 32 + q * 8]);
    f32x4 sacc[4];
#pragma unroll
    for (int t = 0; t < 4; t++) {
        f32x4 a = (f32x4){0,0,0,0};
        a = __builtin_amdgcn_mfma_f32_16x16x32_bf16(ca0, *(const s16x8*)(&sW2b[(t * 16 + ln) * 72 + q * 8]), a, 0, 0, 0);
        a = __builtin_amdgcn_mfma_f32_16x16x32_bf16(ca1, *(const s16x8*)(&sW2b[(t * 16 + ln) * 72 + 32 + q * 8]), a, 0, 0, 0);
        sacc[t] = a;
    }
    float zv[4][4];
    float part4[4] = {0.f, 0.f, 0.f, 0.f};
#pragma unroll
    for (int t = 0; t < 4; t++) {
        float sb = shb[t * 16 + ln];
        float aw = sATT[t * 16 + ln];
#pragma unroll
        for (int r = 0; r < 4; r++) {
            float o = siluf(sacc[t][r] + sb) * posD[t][r];
            zv[t][r] = o;
            part4[r] += o * aw;
        }
    }
    float ab = attb[0];
#pragma unroll
    for (int r = 0; r < 4; r++) {
        float sg = sigmf(quadSum(part4[r]) + ab);
        size_t row = m0 + q * 4 + r;
#pragma unroll
        for (int t = 0; t < 4; t++) {
            float z = zv[t][r] * sg;
            zv[t][r] = z;
            g_z16[row * 64 + t * 16 + ln] = f2bu(z);
        }
    }
#pragma unroll
    for (int hd = 0; hd < 4; hd++) {
#pragma unroll
        for (int r = 0; r < 4; r++) {
            float p = 0.f;
#pragma unroll
            for (int t = 0; t < 4; t++) p += zv[t][r] * sWB[hd * 64 + t * 16 + ln];
            p = quadSum(p);
            if (ln == hd) g_b4[(size_t)(m0 + q * 4 + r) * 4 + hd] = p;
        }
    }
#pragma unroll
    for (int t = 0; t < 4; t++)
#pragma unroll
        for (int r = 0; r < 4; r++)
            T[w][(q * 4 + r) * 72 + t * 16 + ln] = f2bu(posD[t][r]);
    asm volatile("s_waitcnt lgkmcnt(0)" ::: "memory");
    s16x8 pa0 = *(const s16x8*)(&T[w][ln * 72 + q * 8]);
    s16x8 pa1 = *(const s16x8*)(&T[w][ln * 72 + 32 + q * 8]);
    __syncthreads();
    stageP(sW0, g_wmA[3], tid); stageP(sW1b, g_wmA[4], tid); stageP(sW2b, g_wmA[5], tid);
    __syncthreads();
    f32x4 uacc[4];
#pragma unroll
    for (int t = 0; t < 4; t++) {
        f32x4 a = (f32x4){0,0,0,0};
        a = __builtin_amdgcn_mfma_f32_16x16x32_bf16(ca0, *(const s16x8*)(&sW0[(t * 16 + ln) * 72 + q * 8]), a, 0, 0, 0);
        a = __builtin_amdgcn_mfma_f32_16x16x32_bf16(ca1, *(const s16x8*)(&sW0[(t * 16 + ln) * 72 + 32 + q * 8]), a, 0, 0, 0);
        uacc[t] = a;
    }
    float up[4] = {0.f, 0.f, 0.f, 0.f};
#pragma unroll
    for (int t = 0; t < 4; t++) {
        float ub = ub1[t * 16 + ln];
        float w2 = uW2[t * 16 + ln];
#pragma unroll
        for (int r = 0; r < 4; r++) up[r] += siluf(uacc[t][r] + ub) * w2;
    }
    float ub2v = ub2[0];
    float pu[4];
#pragma unroll
    for (int r = 0; r < 4; r++) pu[r] = quadSum(up[r]) + ub2v;
    f32x4 xacc[4], nacc[4];
#pragma unroll
    for (int t = 0; t < 4; t++) {
        f32x4 a = (f32x4){0,0,0,0}, b = (f32x4){0,0,0,0};
        a = __builtin_amdgcn_mfma_f32_16x16x32_bf16(pa0, *(const s16x8*)(&sW1b[(t * 16 + ln) * 72 + q * 8]), a, 0, 0, 0);
        a = __builtin_amdgcn_mfma_f32_16x16x32_bf16(pa1, *(const s16x8*)(&sW1b[(t * 16 + ln) * 72 + 32 + q * 8]), a, 0, 0, 0);
        b = __builtin_amdgcn_mfma_f32_16x16x32_bf16(pa0, *(const s16x8*)(&sW2b[(t * 16 + ln) * 72 + q * 8]), b, 0, 0, 0);
        b = __builtin_amdgcn_mfma_f32_16x16x32_bf16(pa1, *(const s16x8*)(&sW2b[(t * 16 + ln) * 72 + 32 + q * 8]), b, 0, 0, 0);
        xacc[t] = a; nacc[t] = b;
    }
    float xp[4] = {0,0,0,0}, npv[4] = {0,0,0,0};
#pragma unroll
    for (int t = 0; t < 4; t++) {
        float xb = xb1[t * 16 + ln], nb = nb1[t * 16 + ln];
        float xw = xW2[t * 16 + ln], nw = nW2[t * 16 + ln];
#pragma unroll
        for (int r = 0; r < 4; r++) {
            xp[r] += siluf(xacc[t][r] + xb) * xw;
            npv[r] += siluf(nacc[t][r] + nb) * nw;
        }
    }
    float xb2v = xb2[0], nb2v = nb2[0];
#pragma unroll
    for (int r = 0; r < 4; r++) {
        float phix = quadSum(xp[r]) + xb2v;
        float phin = quadSum(npv[r]) + nb2v;
        int row = m0 + q * 4 + r;
        float tx = pu[r] * phix, tn = pu[r] * phin;
        int cc = edges[EE + row];
        if (ln < 3) {
            g_xe[row * 3 + ln] = g_cdl[row * 3 + ln] * tx;
            g_ne[row * 3 + ln] = nvecs[cc * 3 + ln] * tn;
        }
    }
}

// ---------------- attention: 1-wave blocks, fused qp + 2-deep pipeline (frozen: at gather wall) ----------------
struct STG { s16x8 za0, za1, qb0, qb1; f32x4 bv; };

__global__ __launch_bounds__(64) void k_attn2(const int* __restrict__ klist)
{
    __shared__ u16 sQP[16][256];           // qp tile: [edge j][hd*64+d]
    __shared__ u16 zT[16 * 72];
    __shared__ __align__(16) float sA[4][16];
    int lane = threadIdx.x & 63, q = lane >> 4, ln = lane & 15;
    int m0 = blockIdx.x * 16;              // wave owns edges m0..m0+15
    u16* zw = zT;

    // ---- phase 1: qp = z[own] @ M for the 16 own edges (B-frags from global g_Mt, L2-hot) ----
    {
        const u16* zr = g_z16 + (size_t)(m0 + ln) * 64;
        s16x8 af0 = *(const s16x8*)(zr + q * 8);
        s16x8 af1 = *(const s16x8*)(zr + 32 + q * 8);
#pragma unroll
        for (int hd = 0; hd < 4; hd++) {
            f32x4 aM[4];
#pragma unroll
            for (int t = 0; t < 4; t++) {
                f32x4 a = (f32x4){0,0,0,0};
                a = __builtin_amdgcn_mfma_f32_16x16x32_bf16(af0, *(const s16x8*)(&g_Mt[hd][(t * 16 + ln) * 72 + q * 8]), a, 0, 0, 0);
                a = __builtin_amdgcn_mfma_f32_16x16x32_bf16(af1, *(const s16x8*)(&g_Mt[hd][(t * 16 + ln) * 72 + 32 + q * 8]), a, 0, 0, 0);
                aM[t] = a;
            }
#pragma unroll
            for (int t = 0; t < 4; t++)
#pragma unroll
                for (int r = 0; r < 4; r++)
                    sQP[q * 4 + r][hd * 64 + t * 16 + ln] = f2bu(aM[t][r]);
        }
    }
    asm volatile("s_waitcnt lgkmcnt(0)" ::: "memory");

    // ---- phase 2: attention over own 16 edges, 2-deep-ahead pipeline ----
    auto ldkl = [&](int j) -> int {
        return (lane < 32) ? klist[(size_t)(m0 + j) * 32 + lane] : -1;
    };
    auto stage = [&](int kv, int j) -> STG {
        STG s;
        s.za0 = (s16x8){0,0,0,0,0,0,0,0}; s.za1 = (s16x8){0,0,0,0,0,0,0,0};
        s.qb0 = (s16x8){0,0,0,0,0,0,0,0}; s.qb1 = (s16x8){0,0,0,0,0,0,0,0};
        int ij = __shfl(kv, ln);
        if (ij >= 0) {
            const u16* zr = g_z16 + (size_t)ij * 64;
            s.za0 = *(const s16x8*)(zr + q * 8);
            s.za1 = *(const s16x8*)(zr + 32 + q * 8);
        }
        if (ln < 4) {
            s.qb0 = *(const s16x8*)(&sQP[j][ln * 64 + q * 8]);
            s.qb1 = *(const s16x8*)(&sQP[j][ln * 64 + 32 + q * 8]);
        }
        s.bv = (f32x4){0.f, 0.f, 0.f, 0.f};
#pragma unroll
        for (int r = 0; r < 4; r++) {
            int ijj = __shfl(kv, q * 4 + r);
            int jj = __shfl(kv, 16 + q * 4 + r);
            s.bv[r] = (ijj >= 0 && ln < 4) ? g_b4[(size_t)jj * 4 + ln] : 0.f;
        }
        return s;
    };

    int kvA = ldkl(0), kvB = ldkl(1), kvC = ldkl(2);
    STG s0 = stage(kvA, 0);
    STG s1 = stage(kvB, 1);
#pragma unroll 1
    for (int j = 0; j < 16; j++) {
        int kvD = (j + 3 < 16) ? ldkl(j + 3) : -1;
        STG s2;
        if (j + 2 < 16) s2 = stage(kvC, j + 2);
        else {
            s2.za0 = (s16x8){0,0,0,0,0,0,0,0}; s2.za1 = s2.za0;
            s2.qb0 = s2.za0; s2.qb1 = s2.za0;
            s2.bv = (f32x4){0.f, 0.f, 0.f, 0.f};
        }
        // scores (validity folded: za=0 & bv=0 for masked slots -> s=0)
        f32x4 sc = (f32x4){0.f, 0.f, 0.f, 0.f};
        sc = __builtin_amdgcn_mfma_f32_16x16x32_bf16(s0.za0, s0.qb0, sc, 0, 0, 0);
        sc = __builtin_amdgcn_mfma_f32_16x16x32_bf16(s0.za1, s0.qb1, sc, 0, 0, 0);
        *(s16x8*)(&zw[ln * 72 + q * 8]) = s0.za0;
        *(s16x8*)(&zw[ln * 72 + 32 + q * 8]) = s0.za1;
        float s[4];
#pragma unroll
        for (int r = 0; r < 4; r++) s[r] = 0.125f * sc[r] + s0.bv[r];
        float mx = fmaxf(fmaxf(s[0], s[1]), fmaxf(s[2], s[3]));
        mx = fmaxf(mx, __shfl_xor(mx, 16));
        mx = fmaxf(mx, __shfl_xor(mx, 32));
        float ex[4], ps = 0.f;
#pragma unroll
        for (int r = 0; r < 4; r++) { ex[r] = __expf(s[r] - mx); ps += ex[r]; }
        ps += __shfl_xor(ps, 16);
        ps += __shfl_xor(ps, 32);
        float inv = 1.f / ps;
        if (ln < 4)
            *(f32x4*)&sA[ln][q * 4] = (f32x4){ex[0] * inv, ex[1] * inv, ex[2] * inv, ex[3] * inv};
        asm volatile("s_waitcnt lgkmcnt(0)" ::: "memory");
        float t0 = 0.f, t1 = 0.f, t2 = 0.f, t3 = 0.f;
#pragma unroll
        for (int j4 = 0; j4 < 4; j4++) {
            f32x4 a0 = *(const f32x4*)&sA[0][j4 * 4];
            f32x4 a1 = *(const f32x4*)&sA[1][j4 * 4];
            f32x4 a2 = *(const f32x4*)&sA[2][j4 * 4];
            f32x4 a3 = *(const f32x4*)&sA[3][j4 * 4];
#pragma unroll
            for (int r = 0; r < 4; r++) {
                float zz = us2f(zw[(j4 * 4 + r) * 72 + lane]);
                t0 += a0[r] * zz; t1 += a1[r] * zz; t2 += a2[r] * zz; t3 += a3[r] * zz;
            }
        }
        size_t ob = (size_t)(m0 + j) * 64 + lane;
        g_t4[0][ob] = f2bu(t0);
        g_t4[1][ob] = f2bu(t1);
        g_t4[2][ob] = f2bu(t2);
        g_t4[3][ob] = f2bu(t3);
        kvA = kvB; kvB = kvC; kvC = kvD;
        s0 = s1; s1 = s2;
    }
}

// ---------------- fused heads: direct L2-hot global B-operands (no LDS weight staging, no barriers) ----------------
__global__ __launch_bounds__(256) void k_us(
    const float* __restrict__ bg, const int* __restrict__ edges)
{
    __shared__ u16 sU[4][16 * 72];
    int tid = threadIdx.x;
    int lane = tid & 63, q = lane >> 4, ln = lane & 15, w = tid >> 6;
    int m0 = blockIdx.x * 64 + w * 16;
    const u16* zr = g_z16 + (size_t)(m0 + ln) * 64;
    s16x8 za[2];
    za[0] = *(const s16x8*)(zr + q * 8);
    za[1] = *(const s16x8*)(zr + 32 + q * 8);
    f32x4 macc[4];
#pragma unroll
    for (int t = 0; t < 4; t++) macc[t] = (f32x4){0,0,0,0};
    for (int hd = 0; hd < 4; hd++) {
        const u16* wV = g_wpre[hd * 3 + 0];
        const u16* wO = g_wpre[hd * 3 + 1];
        const u16* wG = g_wpre[hd * 3 + 2];
        f32x4 vacc[4], gacc[4];
#pragma unroll
        for (int t = 0; t < 4; t++) { vacc[t] = (f32x4){0,0,0,0}; gacc[t] = (f32x4){0,0,0,0}; }
        const u16* ar = &g_t4[hd][(size_t)(m0 + ln) * 64];
#pragma unroll
        for (int k0 = 0; k0 < 2; k0++) {
            s16x8 af = *(const s16x8*)(ar + k0 * 32 + q * 8);
#pragma unroll
            for (int t = 0; t < 4; t++) {
                vacc[t] = __builtin_amdgcn_mfma_f32_16x16x32_bf16(
                    af, *(const s16x8*)(&wV[(t * 16 + ln) * 72 + k0 * 32 + q * 8]), vacc[t], 0, 0, 0);
                gacc[t] = __builtin_amdgcn_mfma_f32_16x16x32_bf16(
                    za[k0], *(const s16x8*)(&wG[(t * 16 + ln) * 72 + k0 * 32 + q * 8]), gacc[t], 0, 0, 0);
            }
        }
#pragma unroll
        for (int t = 0; t < 4; t++) {
            float bb = bg[hd * 64 + t * 16 + ln];
#pragma unroll
            for (int r = 0; r < 4; r++) {
                float u = vacc[t][r] * sigmf(gacc[t][r] + bb);
                sU[w][(q * 4 + r) * 72 + t * 16 + ln] = f2bu(u);
            }
        }
        asm volatile("s_waitcnt lgkmcnt(0)" ::: "memory");
#pragma unroll
        for (int k0 = 0; k0 < 2; k0++) {
            s16x8 af = *(const s16x8*)(&sU[w][ln * 72 + k0 * 32 + q * 8]);
#pragma unroll
            for (int t = 0; t < 4; t++) {
                macc[t] = __builtin_amdgcn_mfma_f32_16x16x32_bf16(
                    af, *(const s16x8*)(&wO[(t * 16 + ln) * 72 + k0 * 32 + q * 8]), macc[t], 0, 0, 0);
            }
        }
        asm volatile("s_waitcnt lgkmcnt(0)" ::: "memory");
    }
#pragma unroll
    for (int r = 0; r < 4; r++) {
        size_t dst = (size_t)(m0 + q * 4 + r) * 64;
#pragma unroll
        for (int t = 0; t < 4; t++) g_me[dst + t * 16 + ln] = macc[t][r];
    }
}

// ---------------- CSR aggregation: one wave per node; m mean + coord/nvec finalize ----------------
__global__ __launch_bounds__(256) void k_agg(
    const float* __restrict__ coord, const float* __restrict__ nvecs,
    const float* __restrict__ icoord, const float* __restrict__ invecs,
    const float* __restrict__ ob, float* __restrict__ out)
{
    int tid = threadIdx.x;
    int lane = tid & 63;
    int n = blockIdx.x * 4 + (tid >> 6);
    if (n >= NN) return;
    int r0 = g_roff[n], r1 = g_roff[n + 1];
    int deg = r1 - r0;
    float msA = 0.f, msB = 0.f, msC = 0.f, msD = 0.f;
    float xs0 = 0.f, xs1 = 0.f, xs2 = 0.f, ns0 = 0.f, ns1 = 0.f, ns2 = 0.f;
    for (int base = r0; base < r1; base += 64) {
        int idx = base + lane;
        int e_l = (idx < r1) ? g_eid[idx] : -1;
        int cnt = min(64, r1 - base);
        int j = 0;
        for (; j + 3 < cnt; j += 4) {
            int ea = __shfl(e_l, j), eb = __shfl(e_l, j + 1);
            int ec = __shfl(e_l, j + 2), ed = __shfl(e_l, j + 3);
            msA += g_me[(size_t)ea * 64 + lane];
            msB += g_me[(size_t)eb * 64 + lane];
            msC += g_me[(size_t)ec * 64 + lane];
            msD += g_me[(size_t)ed * 64 + lane];
        }
        for (; j < cnt; j++) {
            int ea = __shfl(e_l, j);
            msA += g_me[(size_t)ea * 64 + lane];
        }
        if (e_l >= 0) {
            xs0 += g_xe[e_l * 3 + 0]; xs1 += g_xe[e_l * 3 + 1]; xs2 += g_xe[e_l * 3 + 2];
            ns0 += g_ne[e_l * 3 + 0]; ns1 += g_ne[e_l * 3 + 1]; ns2 += g_ne[e_l * 3 + 2];
        }
    }
    xs0 = waveSum(xs0); xs1 = waveSum(xs1); xs2 = waveSum(xs2);
    ns0 = waveSum(ns0); ns1 = waveSum(ns1); ns2 = waveSum(ns2);
    float rinv = 1.f / fmaxf((float)deg, 1.f);
    float obv = (deg > 0) ? ob[lane] : 0.f;
    g_mavg[(size_t)n * 64 + lane] = (msA + msB + msC + msD) * rinv + obv;
    if (lane == 0) {
        size_t coff = (size_t)NN * 64;
        size_t noff = coff + (size_t)NN * 3;
        float xs[3] = {xs0, xs1, xs2}, ns[3] = {ns0, ns1, ns2};
        float nl[3];
#pragma unroll
        for (int c = 0; c < 3; c++) {
            out[coff + n * 3 + c] = 0.2f * icoord[n * 3 + c] + 0.8f * coord[n * 3 + c] + xs[c] * rinv;
            nl[c] = 0.2f * invecs[n * 3 + c] + 0.8f * nvecs[n * 3 + c] + ns[c] * rinv;
        }
        float nn2 = sqrtf(nl[0] * nl[0] + nl[1] * nl[1] + nl[2] * nl[2]) + 1e-8f;
#pragma unroll
        for (int c = 0; c < 3; c++) out[noff + n * 3 + c] = nl[c] / nn2;
    }
}

// ---------------- node finalize: MFMA MLP over [h|na|m_agg] ----------------
__global__ __launch_bounds__(256) void k_node(
    const float* __restrict__ h, const float* __restrict__ na,
    const float* __restrict__ W1, const float* __restrict__ b1,
    const float* __restrict__ W2, const float* __restrict__ b2,
    float* __restrict__ out)
{
    __shared__ u16 sW1T[64 * 200];
    __shared__ u16 sW2T[64 * 72];
    __shared__ u16 sA[64 * 200];
    __shared__ u16 sT[64 * 72];
    __shared__ float sb2v[64];
    int tid = threadIdx.x;
    int m0 = blockIdx.x * 64;
    for (int i = tid; i < 64 * 192; i += 256) {
        int n = i / 192, k = i - n * 192;
        sW1T[n * 200 + k] = f2bu(W1[k * 64 + n]);
    }
    for (int i = tid; i < 4096; i += 256) {
        int k = i >> 6, n = i & 63;
        sW2T[n * 72 + k] = f2bu(W2[i]);
    }
    if (tid < 64) sb2v[tid] = b2[tid];
    for (int i = tid; i < 4096; i += 256) {
        int row = i >> 6, d = i & 63;
        int n = m0 + row; if (n >= NN) n = NN - 1;
        sA[row * 200 + d] = f2bu(h[(size_t)n * 64 + d]);
        sA[row * 200 + 64 + d] = f2bu(na[(size_t)n * 64 + d]);
        sA[row * 200 + 128 + d] = f2bu(g_mavg[(size_t)n * 64 + d]);
    }
    __syncthreads();
    int lane = tid & 63, q = lane >> 4, ln = lane & 15, w = tid >> 6;
    f32x4 acc[4];
#pragma unroll
    for (int t = 0; t < 4; t++) acc[t] = (f32x4){0.f, 0.f, 0.f, 0.f};
#pragma unroll
    for (int k0 = 0; k0 < 6; k0++) {
        s16x8 af = *(const s16x8*)(&sA[(w * 16 + ln) * 200 + k0 * 32 + q * 8]);
#pragma unroll
        for (int t = 0; t < 4; t++) {
            s16x8 bf = *(const s16x8*)(&sW1T[(t * 16 + ln) * 200 + k0 * 32 + q * 8]);
            acc[t] = __builtin_amdgcn_mfma_f32_16x16x32_bf16(af, bf, acc[t], 0, 0, 0);
        }
    }
#pragma unroll
    for (int t = 0; t < 4; t++) {
        float bv = b1[t * 16 + ln];
#pragma unroll
        for (int r = 0; r < 4; r++)
            sT[(w * 16 + q * 4 + r) * 72 + t * 16 + ln] = f2bu(siluf(acc[t][r] + bv));
    }
    asm volatile("s_waitcnt lgkmcnt(0)" ::: "memory");
    f32x4 acc2[4];
#pragma unroll
    for (int t = 0; t < 4; t++) acc2[t] = (f32x4){0.f, 0.f, 0.f, 0.f};
#pragma unroll
    for (int k0 = 0; k0 < 2; k0++) {
        s16x8 af = *(const s16x8*)(&sT[(w * 16 + ln) * 72 + k0 * 32 + q * 8]);
#pragma unroll
        for (int t = 0; t < 4; t++) {
            s16x8 bf = *(const s16x8*)(&sW2T[(t * 16 + ln) * 72 + k0 * 32 + q * 8]);
            acc2[t] = __builtin_amdgcn_mfma_f32_16x16x32_bf16(af, bf, acc2[t], 0, 0, 0);
        }
    }
#pragma unroll
    for (int r = 0; r < 4; r++) {
        int n = m0 + w * 16 + q * 4 + r;
        if (n < NN) {
#pragma unroll
            for (int t = 0; t < 4; t++) {
                int d = t * 16 + ln;
                out[(size_t)n * 64 + d] = 0.2f * h[(size_t)n * 64 + d] + 0.8f * (acc2[t][r] + sb2v[d]);
            }
        }
    }
}

extern "C" void kernel_launch(void* const* d_in, const int* in_sizes, int n_in,
                              void* d_out, int out_size, void* d_ws, size_t ws_size,
                              hipStream_t stream)
{
    const int* edges = (const int*)d_in[43];
    const int* klist = (const int*)d_in[44];
    auto F = [&](int i) { return (const float*)d_in[i]; };

    k_zero<<<40, 256, 0, stream>>>();
    k_prep<<<512, 256, 0, stream>>>(F(19), F(20), F(0), F(4), F(3), F(1), F(2),
                                    F(21), F(23), F(25),
                                    F(13), F(9), F(15), F(27), F(31), F(35), F(7),
                                    edges);
    k_scan<<<1, 256, 0, stream>>>();
    k_fill<<<782, 256, 0, stream>>>(edges);
    k_chem1<<<1563, 256, 0, stream>>>(edges, F(8));
    k_megaAB<<<3125, 256, 0, stream>>>(F(10), F(11), F(12), F(14),
                                       F(16), F(17), F(18), F(22),
                                       F(28), F(29), F(30),
                                       F(32), F(33), F(34),
                                       F(36), F(37), F(38),
                                       edges, F(2));
    k_attn2<<<12500, 64, 0, stream>>>(klist);
    k_us<<<3125, 256, 0, stream>>>(F(24), edges);
    k_agg<<<2500, 256, 0, stream>>>(F(1), F(2), F(5), F(6), F(26), (float*)d_out);
    k_node<<<157, 256, 0, stream>>>(F(0), F(4), F(39), F(40), F(41), F(42), (float*)d_out);
}

// Round 15
// 609.608 us; speedup vs baseline: 1.0722x; 1.0588x over previous
//
#include <hip/hip_runtime.h>

typedef unsigned short u16;
typedef unsigned int u32;
typedef __attribute__((ext_vector_type(8))) short s16x8;
typedef __attribute__((ext_vector_type(4))) float f32x4;

#define NN 10000
#define EE 200000
#define ES ((size_t)EE * 64)
#define NTILE 3125

#define DEVI __device__ __forceinline__

DEVI float us2f(u16 u) {
    union { u32 i; float f; } v; v.i = ((u32)u) << 16; return v.f;
}
DEVI u16 f2bu(float f) {
    union { float f; u32 i; } v; v.f = f;
    u32 x = v.i;
    return (u16)((x + 0x7fffu + ((x >> 16) & 1u)) >> 16);
}
DEVI float siluf(float x) { return x / (1.f + __expf(-x)); }
DEVI float sigmf(float x) { return 1.f / (1.f + __expf(-x)); }
DEVI float waveSum(float v) {
#pragma unroll
    for (int o = 32; o; o >>= 1) v += __shfl_xor(v, o);
    return v;
}
DEVI float quadSum(float v) {
#pragma unroll
    for (int o = 1; o < 16; o <<= 1) v += __shfl_xor(v, o);
    return v;
}

// ---- module-owned scratch ----
__device__ u16 g_hb[(size_t)NN * 64];
__device__ u16 g_nab[(size_t)NN * 64];
__device__ u16 g_eab[(size_t)EE * 16];
__device__ u16 g_t1[ES];
__device__ u16 g_z16[ES];
__device__ __align__(16) u16 g_Mt[4][4608];     // [hd][n*72+k] bf16 pre-transposed Wq@Wk^T
__device__ __align__(16) u16 g_wpre[12][4608];  // [hd*3+{V,O,G}][n*72+k] bf16 pre-transposed
__device__ __align__(16) u16 g_wmA[6][4608];    // megaAB: posW2,chW2,shW,uW1,xW1,nW1 pre-transposed
__device__ __align__(16) u16 g_w1t[64 * 296];   // chem1 B^T (bf16, padded K to 296)
__device__ float g_b4[(size_t)EE * 4];
__device__ float g_nr[EE];
__device__ float g_rad[EE];
__device__ float g_cdl[EE * 3];
// CSR aggregation
__device__ int g_degi[NN];
__device__ int g_fill[NN];
__device__ int g_roff[NN + 1];
__device__ int g_eid[EE];
__device__ float g_me[(size_t)EE * 64];   // per-edge m rows (fp32)
__device__ float g_xe[EE * 3];
__device__ float g_ne[EE * 3];
__device__ float g_mavg[(size_t)NN * 64];

// ---------------- zero CSR counters ----------------
__global__ __launch_bounds__(256) void k_zero()
{
    int t = blockIdx.x * 256 + threadIdx.x;
    if (t < NN) { g_degi[t] = 0; g_fill[t] = 0; }
}

// ---------------- prep: Mt, weight pre-convert (heads + megaAB + chem1), bf16, geometry, deg ----------------
__global__ __launch_bounds__(256) void k_prep(
    const float* __restrict__ Wq, const float* __restrict__ Wk,
    const float* __restrict__ h, const float* __restrict__ na, const float* __restrict__ ea,
    const float* __restrict__ coord, const float* __restrict__ nvecs,
    const float* __restrict__ Wv, const float* __restrict__ Wg, const float* __restrict__ oW,
    const float* __restrict__ posW2, const float* __restrict__ chW2, const float* __restrict__ shW,
    const float* __restrict__ uW1, const float* __restrict__ xW1, const float* __restrict__ nW1,
    const float* __restrict__ chemW1,
    const int* __restrict__ edges)
{
    int t = blockIdx.x * 256 + threadIdx.x;
    if (t < 16384) {
        int hd = t >> 12, rem = t & 4095, k = rem >> 6, n = rem & 63;
        const float* wq = Wq + (size_t)hd * 4096 + k * 64;
        const float* wk = Wk + (size_t)hd * 4096 + n * 64;
        float acc = 0.f;
        for (int d = 0; d < 64; d++) acc += wq[d] * wk[d];
        int off = n * 72 + k;
        g_Mt[hd][off] = f2bu(acc);
        g_wpre[hd * 3 + 0][off] = f2bu(Wv[t]);
        g_wpre[hd * 3 + 1][off] = f2bu(oW[t]);
        g_wpre[hd * 3 + 2][off] = f2bu(Wg[t]);
    }
    int nt = gridDim.x * 256;
    for (int i = t; i < 6 * 4096; i += nt) {
        int a = i >> 12, rem = i & 4095, k = rem >> 6, n = rem & 63;
        const float* s;
        if (a == 0) s = posW2;
        else if (a == 1) s = chW2;
        else if (a == 2) s = shW;
        else if (a == 3) s = uW1;
        else if (a == 4) s = xW1;
        else s = nW1;
        g_wmA[a][n * 72 + k] = f2bu(s[rem]);
    }
    for (int i = t; i < 64 * 296; i += nt) {
        int n = i / 296, k = i - n * 296;
        g_w1t[i] = (k < 272) ? f2bu(chemW1[k * 64 + n]) : (u16)0;
    }
    for (int i = t; i < NN * 64; i += nt) { g_hb[i] = f2bu(h[i]); g_nab[i] = f2bu(na[i]); }
    for (size_t i = t; i < (size_t)EE * 16; i += nt) g_eab[i] = f2bu(ea[i]);
    for (int e = t; e < EE; e += nt) {
        int r = edges[e], c = edges[EE + e];
        atomicAdd(&g_degi[r], 1);
        float d0 = coord[r * 3 + 0] - coord[c * 3 + 0];
        float d1 = coord[r * 3 + 1] - coord[c * 3 + 1];
        float d2 = coord[r * 3 + 2] - coord[c * 3 + 2];
        float radial = d0 * d0 + d1 * d1 + d2 * d2;
        float np = nvecs[r * 3 + 0] * nvecs[c * 3 + 0]
                 + nvecs[r * 3 + 1] * nvecs[c * 3 + 1]
                 + nvecs[r * 3 + 2] * nvecs[c * 3 + 2];
        float rinv = 1.f / (sqrtf(radial) + 1e-8f);
        g_cdl[e * 3 + 0] = d0 * rinv;
        g_cdl[e * 3 + 1] = d1 * rinv;
        g_cdl[e * 3 + 2] = d2 * rinv;
        g_nr[e] = np;
        g_rad[e] = radial;
    }
}

// ---------------- exclusive scan of degrees (1 block) ----------------
__global__ __launch_bounds__(256) void k_scan()
{
    __shared__ int ls[256];
    int tid = threadIdx.x;
    int basei = tid * 40;
    int loc[40];
    int cnt = 0;
#pragma unroll
    for (int i = 0; i < 40; i++) {
        int idx = basei + i;
        int v = (idx < NN) ? g_degi[idx] : 0;
        loc[i] = cnt; cnt += v;
    }
    ls[tid] = cnt;
    __syncthreads();
    int off = 0;
    for (int i = 0; i < tid; i++) off += ls[i];
#pragma unroll
    for (int i = 0; i < 40; i++) {
        int idx = basei + i;
        if (idx < NN) g_roff[idx] = off + loc[i];
    }
    if (tid == 255) g_roff[NN] = off + cnt;
}

// ---------------- CSR fill ----------------
__global__ __launch_bounds__(256) void k_fill(const int* __restrict__ edges)
{
    int e = blockIdx.x * 256 + threadIdx.x;
    if (e < EE) {
        int r = edges[e];
        int slot = atomicAdd(&g_fill[r], 1);
        g_eid[g_roff[r] + slot] = e;
    }
}

// ---------------- chem layer1: gathered-A GEMM (bf16 sources), K=288, 2 tiles/block ----------------
__global__ __launch_bounds__(256) void k_chem1(
    const int* __restrict__ edges, const float* __restrict__ b1)
{
    __shared__ __align__(16) u16 sBT[64 * 296];
    int tid = threadIdx.x;
    {
        u32* d = (u32*)sBT; const u32* s = (const u32*)g_w1t;
        for (int i = tid; i < 9472; i += 256) d[i] = s[i];
    }
    __syncthreads();
    int lane = tid & 63, q = lane >> 4, ln = lane & 15, w = tid >> 6;
    int base = blockIdx.x * 2;
    int nt2 = (base + 1 < NTILE) ? 2 : 1;
    for (int t2 = 0; t2 < nt2; t2++) {
        int m0 = (base + t2) * 64 + w * 16;
        int e = m0 + ln;
        int r_ = edges[e], c_ = edges[EE + e];
        f32x4 acc[4];
#pragma unroll
        for (int t = 0; t < 4; t++) acc[t] = (f32x4){0.f, 0.f, 0.f, 0.f};
#pragma unroll
        for (int k0 = 0; k0 < 9; k0++) {
            int k = k0 * 32 + q * 8;
            const u16* p = nullptr;
            if (k < 64)       p = g_hb  + (size_t)r_ * 64 + k;
            else if (k < 128) p = g_hb  + (size_t)c_ * 64 + (k - 64);
            else if (k < 192) p = g_nab + (size_t)r_ * 64 + (k - 128);
            else if (k < 256) p = g_nab + (size_t)c_ * 64 + (k - 192);
            else if (k < 272) p = g_eab + (size_t)e * 16 + (k - 256);
            s16x8 af = p ? *(const s16x8*)p : (s16x8){0, 0, 0, 0, 0, 0, 0, 0};
#pragma unroll
            for (int t = 0; t < 4; t++) {
                s16x8 bf = *(const s16x8*)(&sBT[(t * 16 + ln) * 296 + k0 * 32 + q * 8]);
                acc[t] = __builtin_amdgcn_mfma_f32_16x16x32_bf16(af, bf, acc[t], 0, 0, 0);
            }
        }
#pragma unroll
        for (int t = 0; t < 4; t++) {
            float bv = b1[t * 16 + ln];
#pragma unroll
            for (int r = 0; r < 4; r++)
                g_t1[(size_t)(m0 + q * 4 + r) * 64 + t * 16 + ln] = f2bu(siluf(acc[t][r] + bv));
        }
    }
}

// straight u32 copy of pre-converted bf16 weights (covers full 64*72 incl. pad)
DEVI void stageP(u16* dst, const u16* src, int tid) {
    u32* d = (u32*)dst; const u32* s = (const u32*)src;
    for (int i = tid; i < 2304; i += 256) d[i] = s[i];
}

// ---------------- MegaAB: two-phase pre-converted weight staging, 1 tile/block ----------------
__global__ __launch_bounds__(256) void k_megaAB(
    const float* __restrict__ chb2,
    const float* __restrict__ pW1, const float* __restrict__ pb1,
    const float* __restrict__ posb2,
    const float* __restrict__ shb,
    const float* __restrict__ attW, const float* __restrict__ attb,
    const float* __restrict__ Wb,
    const float* __restrict__ ub1, const float* __restrict__ uW2, const float* __restrict__ ub2,
    const float* __restrict__ xb1, const float* __restrict__ xW2, const float* __restrict__ xb2,
    const float* __restrict__ nb1, const float* __restrict__ nW2, const float* __restrict__ nb2,
    const int* __restrict__ edges, const float* __restrict__ nvecs)
{
    __shared__ __align__(16) u16 sW0[64 * 72], sW1b[64 * 72], sW2b[64 * 72];
    __shared__ u16 T[4][16 * 72];
    __shared__ float sWB[256], sATT[64], sPW1[128], sPB1[64];
    int tid = threadIdx.x;
    stageP(sW0, g_wmA[0], tid); stageP(sW1b, g_wmA[1], tid); stageP(sW2b, g_wmA[2], tid);
    sWB[tid] = Wb[tid];
    if (tid < 128) sPW1[tid] = pW1[tid];
    if (tid < 64) { sATT[tid] = attW[tid]; sPB1[tid] = pb1[tid]; }
    __syncthreads();
    int lane = tid & 63, q = lane >> 4, ln = lane & 15, w = tid >> 6;
    int m0 = blockIdx.x * 64 + w * 16;
    float np_ = g_nr[m0 + ln], rad_ = g_rad[m0 + ln];
    s16x8 p1f0, p1f1;
#pragma unroll
    for (int j = 0; j < 8; j++) {
        int k = q * 8 + j;
        p1f0[j] = (short)f2bu(siluf(sPB1[k] + np_ * sPW1[k] + rad_ * sPW1[64 + k]));
        k += 32;
        p1f1[j] = (short)f2bu(siluf(sPB1[k] + np_ * sPW1[k] + rad_ * sPW1[64 + k]));
    }
    f32x4 pacc[4];
#pragma unroll
    for (int t = 0; t < 4; t++) {
        f32x4 a = (f32x4){0,0,0,0};
        a = __builtin_amdgcn_mfma_f32_16x16x32_bf16(p1f0, *(const s16x8*)(&sW0[(t * 16 + ln) * 72 + q * 8]), a, 0, 0, 0);
        a = __builtin_amdgcn_mfma_f32_16x16x32_bf16(p1f1, *(const s16x8*)(&sW0[(t * 16 + ln) * 72 + 32 + q * 8]), a, 0, 0, 0);
        pacc[t] = a;
    }
    float posD[4][4];
#pragma unroll
    for (int t = 0; t < 4; t++) {
        float pb = posb2[t * 16 + ln];
#pragma unroll
        for (int r = 0; r < 4; r++) posD[t][r] = siluf(pacc[t][r] + pb);
    }
    f32x4 cacc[4];
#pragma unroll
    for (int t = 0; t < 4; t++) cacc[t] = (f32x4){0,0,0,0};
    {
        const u16* ar = g_t1 + (size_t)(m0 + ln) * 64;
#pragma unroll
        for (int k0 = 0; k0 < 2; k0++) {
            s16x8 af = *(const s16x8*)(ar + k0 * 32 + q * 8);
#pragma unroll
            for (int t = 0; t < 4; t++) {
                s16x8 bf = *(const s16x8*)(&sW1b[(t * 16 + ln) * 72 + k0 * 32 + q * 8]);
                cacc[t] = __builtin_amdgcn_mfma_f32_16x16x32_bf16(af, bf, cacc[t], 0, 0, 0);
            }
        }
    }
#pragma unroll
    for (int t = 0; t < 4; t++) {
        float cb = chb2[t * 16 + ln];
#pragma unroll
        for (int r = 0; r < 4; r++)
            T[w][(q * 4 + r) * 72 + t * 16 + ln] = f2bu(siluf(cacc[t][r] + cb));
    }
    asm volatile("s_waitcnt lgkmcnt(0)" ::: "memory");
    s16x8 ca0 = *(const s16x8*)(&T[w][ln * 72 + q * 8]);
    s16x8 ca1 = *(const s16x8*)(&T[w][ln * 72 + 32 + q * 8]);
    f32x4 sacc[4];
#pragma unroll
    for (int t = 0; t < 4; t++) {
        f32x4 a = (f32x4){0,0,0,0};
        a = __builtin_amdgcn_mfma_f32_16x16x32_bf16(ca0, *(const s16x8*)(&sW2b[(t * 16 + ln) * 72 + q * 8]), a, 0, 0, 0);
        a = __builtin_amdgcn_mfma_f32_16x16x32_bf16(ca1, *(const s16x8*)(&sW2b[(t * 16 + ln) * 72 + 32 + q * 8]), a, 0, 0, 0);
        sacc[t] = a;
    }
    float zv[4][4];
    float part4[4] = {0.f, 0.f, 0.f, 0.f};
#pragma unroll
    for (int t = 0; t < 4; t++) {
        float sb = shb[t * 16 + ln];
        float aw = sATT[t * 16 + ln];
#pragma unroll
        for (int r = 0; r < 4; r++) {
            float o = siluf(sacc[t][r] + sb) * posD[t][r];
            zv[t][r] = o;
            part4[r] += o * aw;
        }
    }
    float ab = attb[0];
#pragma unroll
    for (int r = 0; r < 4; r++) {
        float sg = sigmf(quadSum(part4[r]) + ab);
        size_t row = m0 + q * 4 + r;
#pragma unroll
        for (int t = 0; t < 4; t++) {
            float z = zv[t][r] * sg;
            zv[t][r] = z;
            g_z16[row * 64 + t * 16 + ln] = f2bu(z);
        }
    }
#pragma unroll
    for (int hd = 0; hd < 4; hd++) {
#pragma unroll
        for (int r = 0; r < 4; r++) {
            float p = 0.f;
#pragma unroll
            for (int t = 0; t < 4; t++) p += zv[t][r] * sWB[hd * 64 + t * 16 + ln];
            p = quadSum(p);
            if (ln == hd) g_b4[(size_t)(m0 + q * 4 + r) * 4 + hd] = p;
        }
    }
#pragma unroll
    for (int t = 0; t < 4; t++)
#pragma unroll
        for (int r = 0; r < 4; r++)
            T[w][(q * 4 + r) * 72 + t * 16 + ln] = f2bu(posD[t][r]);
    asm volatile("s_waitcnt lgkmcnt(0)" ::: "memory");
    s16x8 pa0 = *(const s16x8*)(&T[w][ln * 72 + q * 8]);
    s16x8 pa1 = *(const s16x8*)(&T[w][ln * 72 + 32 + q * 8]);
    __syncthreads();
    stageP(sW0, g_wmA[3], tid); stageP(sW1b, g_wmA[4], tid); stageP(sW2b, g_wmA[5], tid);
    __syncthreads();
    f32x4 uacc[4];
#pragma unroll
    for (int t = 0; t < 4; t++) {
        f32x4 a = (f32x4){0,0,0,0};
        a = __builtin_amdgcn_mfma_f32_16x16x32_bf16(ca0, *(const s16x8*)(&sW0[(t * 16 + ln) * 72 + q * 8]), a, 0, 0, 0);
        a = __builtin_amdgcn_mfma_f32_16x16x32_bf16(ca1, *(const s16x8*)(&sW0[(t * 16 + ln) * 72 + 32 + q * 8]), a, 0, 0, 0);
        uacc[t] = a;
    }
    float up[4] = {0.f, 0.f, 0.f, 0.f};
#pragma unroll
    for (int t = 0; t < 4; t++) {
        float ub = ub1[t * 16 + ln];
        float w2 = uW2[t * 16 + ln];
#pragma unroll
        for (int r = 0; r < 4; r++) up[r] += siluf(uacc[t][r] + ub) * w2;
    }
    float ub2v = ub2[0];
    float pu[4];
#pragma unroll
    for (int r = 0; r < 4; r++) pu[r] = quadSum(up[r]) + ub2v;
    f32x4 xacc[4], nacc[4];
#pragma unroll
    for (int t = 0; t < 4; t++) {
        f32x4 a = (f32x4){0,0,0,0}, b = (f32x4){0,0,0,0};
        a = __builtin_amdgcn_mfma_f32_16x16x32_bf16(pa0, *(const s16x8*)(&sW1b[(t * 16 + ln) * 72 + q * 8]), a, 0, 0, 0);
        a = __builtin_amdgcn_mfma_f32_16x16x32_bf16(pa1, *(const s16x8*)(&sW1b[(t * 16 + ln) * 72 + 32 + q * 8]), a, 0, 0, 0);
        b = __builtin_amdgcn_mfma_f32_16x16x32_bf16(pa0, *(const s16x8*)(&sW2b[(t * 16 + ln) * 72 + q * 8]), b, 0, 0, 0);
        b = __builtin_amdgcn_mfma_f32_16x16x32_bf16(pa1, *(const s16x8*)(&sW2b[(t * 16 + ln) * 72 + 32 + q * 8]), b, 0, 0, 0);
        xacc[t] = a; nacc[t] = b;
    }
    float xp[4] = {0,0,0,0}, npv[4] = {0,0,0,0};
#pragma unroll
    for (int t = 0; t < 4; t++) {
        float xb = xb1[t * 16 + ln], nb = nb1[t * 16 + ln];
        float xw = xW2[t * 16 + ln], nw = nW2[t * 16 + ln];
#pragma unroll
        for (int r = 0; r < 4; r++) {
            xp[r] += siluf(xacc[t][r] + xb) * xw;
            npv[r] += siluf(nacc[t][r] + nb) * nw;
        }
    }
    float xb2v = xb2[0], nb2v = nb2[0];
#pragma unroll
    for (int r = 0; r < 4; r++) {
        float phix = quadSum(xp[r]) + xb2v;
        float phin = quadSum(npv[r]) + nb2v;
        int row = m0 + q * 4 + r;
        float tx = pu[r] * phix, tn = pu[r] * phin;
        int cc = edges[EE + row];
        if (ln < 3) {
            g_xe[row * 3 + ln] = g_cdl[row * 3 + ln] * tx;
            g_ne[row * 3 + ln] = nvecs[cc * 3 + ln] * tn;
        }
    }
}

// ---------------- attention + fused heads: 1-wave blocks, qp + 2-deep pipeline + in-block us ----------------
struct STG { s16x8 za0, za1, qb0, qb1; f32x4 bv; };

__global__ __launch_bounds__(64) void k_attn2(const int* __restrict__ klist,
                                              const float* __restrict__ bg)
{
    __shared__ __align__(16) u16 sQP[16][256];   // qp tile: [edge j][hd*64+d]; reused as u-tile in phase 3
    __shared__ __align__(16) u16 zT[16 * 72];
    __shared__ __align__(16) u16 sT4[4][16 * 72]; // t4 stash: [hd][j*72 + d]
    __shared__ __align__(16) float sA[4][16];
    int lane = threadIdx.x & 63, q = lane >> 4, ln = lane & 15;
    int m0 = blockIdx.x * 16;              // wave owns edges m0..m0+15
    u16* zw = zT;

    // ---- phase 1: qp = z[own] @ M for the 16 own edges (B-frags from global g_Mt, L2-hot) ----
    const u16* zro = g_z16 + (size_t)(m0 + ln) * 64;
    s16x8 zaf0 = *(const s16x8*)(zro + q * 8);       // own z A-fragments: live through phase 3
    s16x8 zaf1 = *(const s16x8*)(zro + 32 + q * 8);
    {
#pragma unroll
        for (int hd = 0; hd < 4; hd++) {
            f32x4 aM[4];
#pragma unroll
            for (int t = 0; t < 4; t++) {
                f32x4 a = (f32x4){0,0,0,0};
                a = __builtin_amdgcn_mfma_f32_16x16x32_bf16(zaf0, *(const s16x8*)(&g_Mt[hd][(t * 16 + ln) * 72 + q * 8]), a, 0, 0, 0);
                a = __builtin_amdgcn_mfma_f32_16x16x32_bf16(zaf1, *(const s16x8*)(&g_Mt[hd][(t * 16 + ln) * 72 + 32 + q * 8]), a, 0, 0, 0);
                aM[t] = a;
            }
#pragma unroll
            for (int t = 0; t < 4; t++)
#pragma unroll
                for (int r = 0; r < 4; r++)
                    sQP[q * 4 + r][hd * 64 + t * 16 + ln] = f2bu(aM[t][r]);
        }
    }
    asm volatile("s_waitcnt lgkmcnt(0)" ::: "memory");

    // ---- phase 2: attention over own 16 edges, 2-deep-ahead pipeline ----
    auto ldkl = [&](int j) -> int {
        return (lane < 32) ? klist[(size_t)(m0 + j) * 32 + lane] : -1;
    };
    auto stage = [&](int kv, int j) -> STG {
        STG s;
        s.za0 = (s16x8){0,0,0,0,0,0,0,0}; s.za1 = (s16x8){0,0,0,0,0,0,0,0};
        s.qb0 = (s16x8){0,0,0,0,0,0,0,0}; s.qb1 = (s16x8){0,0,0,0,0,0,0,0};
        int ij = __shfl(kv, ln);
        if (ij >= 0) {
            const u16* zr = g_z16 + (size_t)ij * 64;
            s.za0 = *(const s16x8*)(zr + q * 8);
            s.za1 = *(const s16x8*)(zr + 32 + q * 8);
        }
        if (ln < 4) {
            s.qb0 = *(const s16x8*)(&sQP[j][ln * 64 + q * 8]);
            s.qb1 = *(const s16x8*)(&sQP[j][ln * 64 + 32 + q * 8]);
        }
        s.bv = (f32x4){0.f, 0.f, 0.f, 0.f};
#pragma unroll
        for (int r = 0; r < 4; r++) {
            int ijj = __shfl(kv, q * 4 + r);
            int jj = __shfl(kv, 16 + q * 4 + r);
            s.bv[r] = (ijj >= 0 && ln < 4) ? g_b4[(size_t)jj * 4 + ln] : 0.f;
        }
        return s;
    };

    int kvA = ldkl(0), kvB = ldkl(1), kvC = ldkl(2);
    STG s0 = stage(kvA, 0);
    STG s1 = stage(kvB, 1);
#pragma unroll 1
    for (int j = 0; j < 16; j++) {
        int kvD = (j + 3 < 16) ? ldkl(j + 3) : -1;
        STG s2;
        if (j + 2 < 16) s2 = stage(kvC, j + 2);
        else {
            s2.za0 = (s16x8){0,0,0,0,0,0,0,0}; s2.za1 = s2.za0;
            s2.qb0 = s2.za0; s2.qb1 = s2.za0;
            s2.bv = (f32x4){0.f, 0.f, 0.f, 0.f};
        }
        // scores (validity folded: za=0 & bv=0 for masked slots -> s=0)
        f32x4 sc = (f32x4){0.f, 0.f, 0.f, 0.f};
        sc = __builtin_amdgcn_mfma_f32_16x16x32_bf16(s0.za0, s0.qb0, sc, 0, 0, 0);
        sc = __builtin_amdgcn_mfma_f32_16x16x32_bf16(s0.za1, s0.qb1, sc, 0, 0, 0);
        *(s16x8*)(&zw[ln * 72 + q * 8]) = s0.za0;
        *(s16x8*)(&zw[ln * 72 + 32 + q * 8]) = s0.za1;
        float s[4];
#pragma unroll
        for (int r = 0; r < 4; r++) s[r] = 0.125f * sc[r] + s0.bv[r];
        float mx = fmaxf(fmaxf(s[0], s[1]), fmaxf(s[2], s[3]));
        mx = fmaxf(mx, __shfl_xor(mx, 16));
        mx = fmaxf(mx, __shfl_xor(mx, 32));
        float ex[4], ps = 0.f;
#pragma unroll
        for (int r = 0; r < 4; r++) { ex[r] = __expf(s[r] - mx); ps += ex[r]; }
        ps += __shfl_xor(ps, 16);
        ps += __shfl_xor(ps, 32);
        float inv = 1.f / ps;
        if (ln < 4)
            *(f32x4*)&sA[ln][q * 4] = (f32x4){ex[0] * inv, ex[1] * inv, ex[2] * inv, ex[3] * inv};
        asm volatile("s_waitcnt lgkmcnt(0)" ::: "memory");
        float t0 = 0.f, t1 = 0.f, t2 = 0.f, t3 = 0.f;
#pragma unroll
        for (int j4 = 0; j4 < 4; j4++) {
            f32x4 a0 = *(const f32x4*)&sA[0][j4 * 4];
            f32x4 a1 = *(const f32x4*)&sA[1][j4 * 4];
            f32x4 a2 = *(const f32x4*)&sA[2][j4 * 4];
            f32x4 a3 = *(const f32x4*)&sA[3][j4 * 4];
#pragma unroll
            for (int r = 0; r < 4; r++) {
                float zz = us2f(zw[(j4 * 4 + r) * 72 + lane]);
                t0 += a0[r] * zz; t1 += a1[r] * zz; t2 += a2[r] * zz; t3 += a3[r] * zz;
            }
        }
        // stash t4 rows in LDS (replaces global t4 round-trip)
        sT4[0][j * 72 + lane] = f2bu(t0);
        sT4[1][j * 72 + lane] = f2bu(t1);
        sT4[2][j * 72 + lane] = f2bu(t2);
        sT4[3][j * 72 + lane] = f2bu(t3);
        kvA = kvB; kvB = kvC; kvC = kvD;
        s0 = s1; s1 = s2;
    }

    // ---- phase 3: fused heads  u=(t@Wv)*sigm(z@Wg+bg); m=Σ_hd u@oW_hd ----
    asm volatile("s_waitcnt lgkmcnt(0)" ::: "memory");
    u16* uT = &sQP[0][0];   // sQP dead after phase 2; reuse first 16*72 u16 as u-tile
    f32x4 macc[4];
#pragma unroll
    for (int t = 0; t < 4; t++) macc[t] = (f32x4){0,0,0,0};
    for (int hd = 0; hd < 4; hd++) {
        const u16* wV = g_wpre[hd * 3 + 0];
        const u16* wO = g_wpre[hd * 3 + 1];
        const u16* wG = g_wpre[hd * 3 + 2];
        f32x4 vacc[4], gacc[4];
#pragma unroll
        for (int t = 0; t < 4; t++) { vacc[t] = (f32x4){0,0,0,0}; gacc[t] = (f32x4){0,0,0,0}; }
#pragma unroll
        for (int k0 = 0; k0 < 2; k0++) {
            s16x8 af = *(const s16x8*)(&sT4[hd][ln * 72 + k0 * 32 + q * 8]);
            s16x8 zf = (k0 == 0) ? zaf0 : zaf1;
#pragma unroll
            for (int t = 0; t < 4; t++) {
                vacc[t] = __builtin_amdgcn_mfma_f32_16x16x32_bf16(
                    af, *(const s16x8*)(&wV[(t * 16 + ln) * 72 + k0 * 32 + q * 8]), vacc[t], 0, 0, 0);
                gacc[t] = __builtin_amdgcn_mfma_f32_16x16x32_bf16(
                    zf, *(const s16x8*)(&wG[(t * 16 + ln) * 72 + k0 * 32 + q * 8]), gacc[t], 0, 0, 0);
            }
        }
#pragma unroll
        for (int t = 0; t < 4; t++) {
            float bb = bg[hd * 64 + t * 16 + ln];
#pragma unroll
            for (int r = 0; r < 4; r++) {
                float u = vacc[t][r] * sigmf(gacc[t][r] + bb);
                uT[(q * 4 + r) * 72 + t * 16 + ln] = f2bu(u);
            }
        }
        asm volatile("s_waitcnt lgkmcnt(0)" ::: "memory");
#pragma unroll
        for (int k0 = 0; k0 < 2; k0++) {
            s16x8 af = *(const s16x8*)(&uT[ln * 72 + k0 * 32 + q * 8]);
#pragma unroll
            for (int t = 0; t < 4; t++) {
                macc[t] = __builtin_amdgcn_mfma_f32_16x16x32_bf16(
                    af, *(const s16x8*)(&wO[(t * 16 + ln) * 72 + k0 * 32 + q * 8]), macc[t], 0, 0, 0);
            }
        }
        asm volatile("s_waitcnt lgkmcnt(0)" ::: "memory");
    }
#pragma unroll
    for (int r = 0; r < 4; r++) {
        size_t dst = (size_t)(m0 + q * 4 + r) * 64;
#pragma unroll
        for (int t = 0; t < 4; t++) g_me[dst + t * 16 + ln] = macc[t][r];
    }
}

// ---------------- CSR aggregation: one wave per node; m mean + coord/nvec finalize ----------------
__global__ __launch_bounds__(256) void k_agg(
    const float* __restrict__ coord, const float* __restrict__ nvecs,
    const float* __restrict__ icoord, const float* __restrict__ invecs,
    const float* __restrict__ ob, float* __restrict__ out)
{
    int tid = threadIdx.x;
    int lane = tid & 63;
    int n = blockIdx.x * 4 + (tid >> 6);
    if (n >= NN) return;
    int r0 = g_roff[n], r1 = g_roff[n + 1];
    int deg = r1 - r0;
    float msA = 0.f, msB = 0.f, msC = 0.f, msD = 0.f;
    float xs0 = 0.f, xs1 = 0.f, xs2 = 0.f, ns0 = 0.f, ns1 = 0.f, ns2 = 0.f;
    for (int base = r0; base < r1; base += 64) {
        int idx = base + lane;
        int e_l = (idx < r1) ? g_eid[idx] : -1;
        int cnt = min(64, r1 - base);
        int j = 0;
        for (; j + 3 < cnt; j += 4) {
            int ea = __shfl(e_l, j), eb = __shfl(e_l, j + 1);
            int ec = __shfl(e_l, j + 2), ed = __shfl(e_l, j + 3);
            msA += g_me[(size_t)ea * 64 + lane];
            msB += g_me[(size_t)eb * 64 + lane];
            msC += g_me[(size_t)ec * 64 + lane];
            msD += g_me[(size_t)ed * 64 + lane];
        }
        for (; j < cnt; j++) {
            int ea = __shfl(e_l, j);
            msA += g_me[(size_t)ea * 64 + lane];
        }
        if (e_l >= 0) {
            xs0 += g_xe[e_l * 3 + 0]; xs1 += g_xe[e_l * 3 + 1]; xs2 += g_xe[e_l * 3 + 2];
            ns0 += g_ne[e_l * 3 + 0]; ns1 += g_ne[e_l * 3 + 1]; ns2 += g_ne[e_l * 3 + 2];
        }
    }
    xs0 = waveSum(xs0); xs1 = waveSum(xs1); xs2 = waveSum(xs2);
    ns0 = waveSum(ns0); ns1 = waveSum(ns1); ns2 = waveSum(ns2);
    float rinv = 1.f / fmaxf((float)deg, 1.f);
    float obv = (deg > 0) ? ob[lane] : 0.f;
    g_mavg[(size_t)n * 64 + lane] = (msA + msB + msC + msD) * rinv + obv;
    if (lane == 0) {
        size_t coff = (size_t)NN * 64;
        size_t noff = coff + (size_t)NN * 3;
        float xs[3] = {xs0, xs1, xs2}, ns[3] = {ns0, ns1, ns2};
        float nl[3];
#pragma unroll
        for (int c = 0; c < 3; c++) {
            out[coff + n * 3 + c] = 0.2f * icoord[n * 3 + c] + 0.8f * coord[n * 3 + c] + xs[c] * rinv;
            nl[c] = 0.2f * invecs[n * 3 + c] + 0.8f * nvecs[n * 3 + c] + ns[c] * rinv;
        }
        float nn2 = sqrtf(nl[0] * nl[0] + nl[1] * nl[1] + nl[2] * nl[2]) + 1e-8f;
#pragma unroll
        for (int c = 0; c < 3; c++) out[noff + n * 3 + c] = nl[c] / nn2;
    }
}

// ---------------- node finalize: MFMA MLP over [h|na|m_agg] ----------------
__global__ __launch_bounds__(256) void k_node(
    const float* __restrict__ h, const float* __restrict__ na,
    const float* __restrict__ W1, const float* __restrict__ b1,
    const float* __restrict__ W2, const float* __restrict__ b2,
    float* __restrict__ out)
{
    __shared__ u16 sW1T[64 * 200];
    __shared__ u16 sW2T[64 * 72];
    __shared__ u16 sA[64 * 200];
    __shared__ u16 sT[64 * 72];
    __shared__ float sb2v[64];
    int tid = threadIdx.x;
    int m0 = blockIdx.x * 64;
    for (int i = tid; i < 64 * 192; i += 256) {
        int n = i / 192, k = i - n * 192;
        sW1T[n * 200 + k] = f2bu(W1[k * 64 + n]);
    }
    for (int i = tid; i < 4096; i += 256) {
        int k = i >> 6, n = i & 63;
        sW2T[n * 72 + k] = f2bu(W2[i]);
    }
    if (tid < 64) sb2v[tid] = b2[tid];
    for (int i = tid; i < 4096; i += 256) {
        int row = i >> 6, d = i & 63;
        int n = m0 + row; if (n >= NN) n = NN - 1;
        sA[row * 200 + d] = f2bu(h[(size_t)n * 64 + d]);
        sA[row * 200 + 64 + d] = f2bu(na[(size_t)n * 64 + d]);
        sA[row * 200 + 128 + d] = f2bu(g_mavg[(size_t)n * 64 + d]);
    }
    __syncthreads();
    int lane = tid & 63, q = lane >> 4, ln = lane & 15, w = tid >> 6;
    f32x4 acc[4];
#pragma unroll
    for (int t = 0; t < 4; t++) acc[t] = (f32x4){0.f, 0.f, 0.f, 0.f};
#pragma unroll
    for (int k0 = 0; k0 < 6; k0++) {
        s16x8 af = *(const s16x8*)(&sA[(w * 16 + ln) * 200 + k0 * 32 + q * 8]);
#pragma unroll
        for (int t = 0; t < 4; t++) {
            s16x8 bf = *(const s16x8*)(&sW1T[(t * 16 + ln) * 200 + k0 * 32 + q * 8]);
            acc[t] = __builtin_amdgcn_mfma_f32_16x16x32_bf16(af, bf, acc[t], 0, 0, 0);
        }
    }
#pragma unroll
    for (int t = 0; t < 4; t++) {
        float bv = b1[t * 16 + ln];
#pragma unroll
        for (int r = 0; r < 4; r++)
            sT[(w * 16 + q * 4 + r) * 72 + t * 16 + ln] = f2bu(siluf(acc[t][r] + bv));
    }
    asm volatile("s_waitcnt lgkmcnt(0)" ::: "memory");
    f32x4 acc2[4];
#pragma unroll
    for (int t = 0; t < 4; t++) acc2[t] = (f32x4){0.f, 0.f, 0.f, 0.f};
#pragma unroll
    for (int k0 = 0; k0 < 2; k0++) {
        s16x8 af = *(const s16x8*)(&sT[(w * 16 + ln) * 72 + k0 * 32 + q * 8]);
#pragma unroll
        for (int t = 0; t < 4; t++) {
            s16x8 bf = *(const s16x8*)(&sW2T[(t * 16 + ln) * 72 + k0 * 32 + q * 8]);
            acc2[t] = __builtin_amdgcn_mfma_f32_16x16x32_bf16(af, bf, acc2[t], 0, 0, 0);
        }
    }
#pragma unroll
    for (int r = 0; r < 4; r++) {
        int n = m0 + w * 16 + q * 4 + r;
        if (n < NN) {
#pragma unroll
            for (int t = 0; t < 4; t++) {
                int d = t * 16 + ln;
                out[(size_t)n * 64 + d] = 0.2f * h[(size_t)n * 64 + d] + 0.8f * (acc2[t][r] + sb2v[d]);
            }
        }
    }
}

extern "C" void kernel_launch(void* const* d_in, const int* in_sizes, int n_in,
                              void* d_out, int out_size, void* d_ws, size_t ws_size,
                              hipStream_t stream)
{
    const int* edges = (const int*)d_in[43];
    const int* klist = (const int*)d_in[44];
    auto F = [&](int i) { return (const float*)d_in[i]; };

    k_zero<<<40, 256, 0, stream>>>();
    k_prep<<<512, 256, 0, stream>>>(F(19), F(20), F(0), F(4), F(3), F(1), F(2),
                                    F(21), F(23), F(25),
                                    F(13), F(9), F(15), F(27), F(31), F(35), F(7),
                                    edges);
    k_scan<<<1, 256, 0, stream>>>();
    k_fill<<<782, 256, 0, stream>>>(edges);
    k_chem1<<<1563, 256, 0, stream>>>(edges, F(8));
    k_megaAB<<<3125, 256, 0, stream>>>(F(10), F(11), F(12), F(14),
                                       F(16), F(17), F(18), F(22),
                                       F(28), F(29), F(30),
                                       F(32), F(33), F(34),
                                       F(36), F(37), F(38),
                                       edges, F(2));
    k_attn2<<<12500, 64, 0, stream>>>(klist, F(24));
    k_agg<<<2500, 256, 0, stream>>>(F(1), F(2), F(5), F(6), F(26), (float*)d_out);
    k_node<<<157, 256, 0, stream>>>(F(0), F(4), F(39), F(40), F(41), F(42), (float*)d_out);
}

// Round 16
// 605.929 us; speedup vs baseline: 1.0787x; 1.0061x over previous
//
#include <hip/hip_runtime.h>

typedef unsigned short u16;
typedef unsigned int u32;
typedef __attribute__((ext_vector_type(8))) short s16x8;
typedef __attribute__((ext_vector_type(4))) float f32x4;

#define NN 10000
#define EE 200000
#define ES ((size_t)EE * 64)
#define NTILE 3125

#define DEVI __device__ __forceinline__

DEVI float us2f(u16 u) {
    union { u32 i; float f; } v; v.i = ((u32)u) << 16; return v.f;
}
DEVI u16 f2bu(float f) {
    union { float f; u32 i; } v; v.f = f;
    u32 x = v.i;
    return (u16)((x + 0x7fffu + ((x >> 16) & 1u)) >> 16);
}
DEVI float siluf(float x) { return x / (1.f + __expf(-x)); }
DEVI float sigmf(float x) { return 1.f / (1.f + __expf(-x)); }
DEVI float waveSum(float v) {
#pragma unroll
    for (int o = 32; o; o >>= 1) v += __shfl_xor(v, o);
    return v;
}
DEVI float quadSum(float v) {
#pragma unroll
    for (int o = 1; o < 16; o <<= 1) v += __shfl_xor(v, o);
    return v;
}

// ---- module-owned scratch ----
__device__ u16 g_hb[(size_t)NN * 64];
__device__ u16 g_nab[(size_t)NN * 64];
__device__ u16 g_eab[(size_t)EE * 16];
__device__ u16 g_t1[ES];
__device__ u16 g_z16[ES];
__device__ __align__(16) u16 g_Mt[4][4608];     // [hd][n*72+k] bf16 pre-transposed Wq@Wk^T
__device__ __align__(16) u16 g_wpre[12][4608];  // [hd*3+{V,O,G}][n*72+k] bf16 pre-transposed
__device__ __align__(16) u16 g_wmA[6][4608];    // megaAB: posW2,chW2,shW,uW1,xW1,nW1 pre-transposed
__device__ __align__(16) u16 g_w1t[64 * 296];   // chem1 B^T (bf16, padded K to 296)
__device__ float g_b4[(size_t)EE * 4];
__device__ float g_nr[EE];
__device__ float g_rad[EE];
__device__ float g_cdl[EE * 3];
// CSR aggregation
__device__ int g_degi[NN];
__device__ int g_fill[NN];
__device__ int g_roff[NN + 1];
__device__ int g_eid[EE];
__device__ u16 g_me16[(size_t)EE * 64]; // per-edge m rows (bf16; k_node rounds m_agg to bf16 anyway)
__device__ float g_xe[EE * 3];
__device__ float g_ne[EE * 3];
__device__ float g_mavg[(size_t)NN * 64];

// ---------------- zero CSR counters ----------------
__global__ __launch_bounds__(256) void k_zero()
{
    int t = blockIdx.x * 256 + threadIdx.x;
    if (t < NN) { g_degi[t] = 0; g_fill[t] = 0; }
}

// ---------------- prep: Mt, weight pre-convert (heads + megaAB + chem1), bf16, geometry, deg ----------------
__global__ __launch_bounds__(256) void k_prep(
    const float* __restrict__ Wq, const float* __restrict__ Wk,
    const float* __restrict__ h, const float* __restrict__ na, const float* __restrict__ ea,
    const float* __restrict__ coord, const float* __restrict__ nvecs,
    const float* __restrict__ Wv, const float* __restrict__ Wg, const float* __restrict__ oW,
    const float* __restrict__ posW2, const float* __restrict__ chW2, const float* __restrict__ shW,
    const float* __restrict__ uW1, const float* __restrict__ xW1, const float* __restrict__ nW1,
    const float* __restrict__ chemW1,
    const int* __restrict__ edges)
{
    int t = blockIdx.x * 256 + threadIdx.x;
    if (t < 16384) {
        int hd = t >> 12, rem = t & 4095, k = rem >> 6, n = rem & 63;
        const float* wq = Wq + (size_t)hd * 4096 + k * 64;
        const float* wk = Wk + (size_t)hd * 4096 + n * 64;
        float acc = 0.f;
        for (int d = 0; d < 64; d++) acc += wq[d] * wk[d];
        int off = n * 72 + k;
        g_Mt[hd][off] = f2bu(acc);
        g_wpre[hd * 3 + 0][off] = f2bu(Wv[t]);
        g_wpre[hd * 3 + 1][off] = f2bu(oW[t]);
        g_wpre[hd * 3 + 2][off] = f2bu(Wg[t]);
    }
    int nt = gridDim.x * 256;
    for (int i = t; i < 6 * 4096; i += nt) {
        int a = i >> 12, rem = i & 4095, k = rem >> 6, n = rem & 63;
        const float* s;
        if (a == 0) s = posW2;
        else if (a == 1) s = chW2;
        else if (a == 2) s = shW;
        else if (a == 3) s = uW1;
        else if (a == 4) s = xW1;
        else s = nW1;
        g_wmA[a][n * 72 + k] = f2bu(s[rem]);
    }
    for (int i = t; i < 64 * 296; i += nt) {
        int n = i / 296, k = i - n * 296;
        g_w1t[i] = (k < 272) ? f2bu(chemW1[k * 64 + n]) : (u16)0;
    }
    for (int i = t; i < NN * 64; i += nt) { g_hb[i] = f2bu(h[i]); g_nab[i] = f2bu(na[i]); }
    for (size_t i = t; i < (size_t)EE * 16; i += nt) g_eab[i] = f2bu(ea[i]);
    for (int e = t; e < EE; e += nt) {
        int r = edges[e], c = edges[EE + e];
        atomicAdd(&g_degi[r], 1);
        float d0 = coord[r * 3 + 0] - coord[c * 3 + 0];
        float d1 = coord[r * 3 + 1] - coord[c * 3 + 1];
        float d2 = coord[r * 3 + 2] - coord[c * 3 + 2];
        float radial = d0 * d0 + d1 * d1 + d2 * d2;
        float np = nvecs[r * 3 + 0] * nvecs[c * 3 + 0]
                 + nvecs[r * 3 + 1] * nvecs[c * 3 + 1]
                 + nvecs[r * 3 + 2] * nvecs[c * 3 + 2];
        float rinv = 1.f / (sqrtf(radial) + 1e-8f);
        g_cdl[e * 3 + 0] = d0 * rinv;
        g_cdl[e * 3 + 1] = d1 * rinv;
        g_cdl[e * 3 + 2] = d2 * rinv;
        g_nr[e] = np;
        g_rad[e] = radial;
    }
}

// ---------------- exclusive scan of degrees (1 block) ----------------
__global__ __launch_bounds__(256) void k_scan()
{
    __shared__ int ls[256];
    int tid = threadIdx.x;
    int basei = tid * 40;
    int loc[40];
    int cnt = 0;
#pragma unroll
    for (int i = 0; i < 40; i++) {
        int idx = basei + i;
        int v = (idx < NN) ? g_degi[idx] : 0;
        loc[i] = cnt; cnt += v;
    }
    ls[tid] = cnt;
    __syncthreads();
    int off = 0;
    for (int i = 0; i < tid; i++) off += ls[i];
#pragma unroll
    for (int i = 0; i < 40; i++) {
        int idx = basei + i;
        if (idx < NN) g_roff[idx] = off + loc[i];
    }
    if (tid == 255) g_roff[NN] = off + cnt;
}

// ---------------- CSR fill ----------------
__global__ __launch_bounds__(256) void k_fill(const int* __restrict__ edges)
{
    int e = blockIdx.x * 256 + threadIdx.x;
    if (e < EE) {
        int r = edges[e];
        int slot = atomicAdd(&g_fill[r], 1);
        g_eid[g_roff[r] + slot] = e;
    }
}

// ---------------- chem layer1: gathered-A GEMM (bf16 sources), K=288, 2 tiles/block ----------------
__global__ __launch_bounds__(256) void k_chem1(
    const int* __restrict__ edges, const float* __restrict__ b1)
{
    __shared__ __align__(16) u16 sBT[64 * 296];
    int tid = threadIdx.x;
    {
        u32* d = (u32*)sBT; const u32* s = (const u32*)g_w1t;
        for (int i = tid; i < 9472; i += 256) d[i] = s[i];
    }
    __syncthreads();
    int lane = tid & 63, q = lane >> 4, ln = lane & 15, w = tid >> 6;
    int base = blockIdx.x * 2;
    int nt2 = (base + 1 < NTILE) ? 2 : 1;
    for (int t2 = 0; t2 < nt2; t2++) {
        int m0 = (base + t2) * 64 + w * 16;
        int e = m0 + ln;
        int r_ = edges[e], c_ = edges[EE + e];
        f32x4 acc[4];
#pragma unroll
        for (int t = 0; t < 4; t++) acc[t] = (f32x4){0.f, 0.f, 0.f, 0.f};
#pragma unroll
        for (int k0 = 0; k0 < 9; k0++) {
            int k = k0 * 32 + q * 8;
            const u16* p = nullptr;
            if (k < 64)       p = g_hb  + (size_t)r_ * 64 + k;
            else if (k < 128) p = g_hb  + (size_t)c_ * 64 + (k - 64);
            else if (k < 192) p = g_nab + (size_t)r_ * 64 + (k - 128);
            else if (k < 256) p = g_nab + (size_t)c_ * 64 + (k - 192);
            else if (k < 272) p = g_eab + (size_t)e * 16 + (k - 256);
            s16x8 af = p ? *(const s16x8*)p : (s16x8){0, 0, 0, 0, 0, 0, 0, 0};
#pragma unroll
            for (int t = 0; t < 4; t++) {
                s16x8 bf = *(const s16x8*)(&sBT[(t * 16 + ln) * 296 + k0 * 32 + q * 8]);
                acc[t] = __builtin_amdgcn_mfma_f32_16x16x32_bf16(af, bf, acc[t], 0, 0, 0);
            }
        }
#pragma unroll
        for (int t = 0; t < 4; t++) {
            float bv = b1[t * 16 + ln];
#pragma unroll
            for (int r = 0; r < 4; r++)
                g_t1[(size_t)(m0 + q * 4 + r) * 64 + t * 16 + ln] = f2bu(siluf(acc[t][r] + bv));
        }
    }
}

// straight u32 copy of pre-converted bf16 weights (covers full 64*72 incl. pad)
DEVI void stageP(u16* dst, const u16* src, int tid) {
    u32* d = (u32*)dst; const u32* s = (const u32*)src;
    for (int i = tid; i < 2304; i += 256) d[i] = s[i];
}

// ---------------- MegaAB: two-phase pre-converted weight staging, 1 tile/block ----------------
__global__ __launch_bounds__(256) void k_megaAB(
    const float* __restrict__ chb2,
    const float* __restrict__ pW1, const float* __restrict__ pb1,
    const float* __restrict__ posb2,
    const float* __restrict__ shb,
    const float* __restrict__ attW, const float* __restrict__ attb,
    const float* __restrict__ Wb,
    const float* __restrict__ ub1, const float* __restrict__ uW2, const float* __restrict__ ub2,
    const float* __restrict__ xb1, const float* __restrict__ xW2, const float* __restrict__ xb2,
    const float* __restrict__ nb1, const float* __restrict__ nW2, const float* __restrict__ nb2,
    const int* __restrict__ edges, const float* __restrict__ nvecs)
{
    __shared__ __align__(16) u16 sW0[64 * 72], sW1b[64 * 72], sW2b[64 * 72];
    __shared__ u16 T[4][16 * 72];
    __shared__ float sWB[256], sATT[64], sPW1[128], sPB1[64];
    int tid = threadIdx.x;
    stageP(sW0, g_wmA[0], tid); stageP(sW1b, g_wmA[1], tid); stageP(sW2b, g_wmA[2], tid);
    sWB[tid] = Wb[tid];
    if (tid < 128) sPW1[tid] = pW1[tid];
    if (tid < 64) { sATT[tid] = attW[tid]; sPB1[tid] = pb1[tid]; }
    __syncthreads();
    int lane = tid & 63, q = lane >> 4, ln = lane & 15, w = tid >> 6;
    int m0 = blockIdx.x * 64 + w * 16;
    float np_ = g_nr[m0 + ln], rad_ = g_rad[m0 + ln];
    s16x8 p1f0, p1f1;
#pragma unroll
    for (int j = 0; j < 8; j++) {
        int k = q * 8 + j;
        p1f0[j] = (short)f2bu(siluf(sPB1[k] + np_ * sPW1[k] + rad_ * sPW1[64 + k]));
        k += 32;
        p1f1[j] = (short)f2bu(siluf(sPB1[k] + np_ * sPW1[k] + rad_ * sPW1[64 + k]));
    }
    f32x4 pacc[4];
#pragma unroll
    for (int t = 0; t < 4; t++) {
        f32x4 a = (f32x4){0,0,0,0};
        a = __builtin_amdgcn_mfma_f32_16x16x32_bf16(p1f0, *(const s16x8*)(&sW0[(t * 16 + ln) * 72 + q * 8]), a, 0, 0, 0);
        a = __builtin_amdgcn_mfma_f32_16x16x32_bf16(p1f1, *(const s16x8*)(&sW0[(t * 16 + ln) * 72 + 32 + q * 8]), a, 0, 0, 0);
        pacc[t] = a;
    }
    float posD[4][4];
#pragma unroll
    for (int t = 0; t < 4; t++) {
        float pb = posb2[t * 16 + ln];
#pragma unroll
        for (int r = 0; r < 4; r++) posD[t][r] = siluf(pacc[t][r] + pb);
    }
    f32x4 cacc[4];
#pragma unroll
    for (int t = 0; t < 4; t++) cacc[t] = (f32x4){0,0,0,0};
    {
        const u16* ar = g_t1 + (size_t)(m0 + ln) * 64;
#pragma unroll
        for (int k0 = 0; k0 < 2; k0++) {
            s16x8 af = *(const s16x8*)(ar + k0 * 32 + q * 8);
#pragma unroll
            for (int t = 0; t < 4; t++) {
                s16x8 bf = *(const s16x8*)(&sW1b[(t * 16 + ln) * 72 + k0 * 32 + q * 8]);
                cacc[t] = __builtin_amdgcn_mfma_f32_16x16x32_bf16(af, bf, cacc[t], 0, 0, 0);
            }
        }
    }
#pragma unroll
    for (int t = 0; t < 4; t++) {
        float cb = chb2[t * 16 + ln];
#pragma unroll
        for (int r = 0; r < 4; r++)
            T[w][(q * 4 + r) * 72 + t * 16 + ln] = f2bu(siluf(cacc[t][r] + cb));
    }
    asm volatile("s_waitcnt lgkmcnt(0)" ::: "memory");
    s16x8 ca0 = *(const s16x8*)(&T[w][ln * 72 + q * 8]);
    s16x8 ca1 = *(const s16x8*)(&T[w][ln * 72 + 32 + q * 8]);
    f32x4 sacc[4];
#pragma unroll
    for (int t = 0; t < 4; t++) {
        f32x4 a = (f32x4){0,0,0,0};
        a = __builtin_amdgcn_mfma_f32_16x16x32_bf16(ca0, *(const s16x8*)(&sW2b[(t * 16 + ln) * 72 + q * 8]), a, 0, 0, 0);
        a = __builtin_amdgcn_mfma_f32_16x16x32_bf16(ca1, *(const s16x8*)(&sW2b[(t * 16 + ln) * 72 + 32 + q * 8]), a, 0, 0, 0);
        sacc[t] = a;
    }
    float zv[4][4];
    float part4[4] = {0.f, 0.f, 0.f, 0.f};
#pragma unroll
    for (int t = 0; t < 4; t++) {
        float sb = shb[t * 16 + ln];
        float aw = sATT[t * 16 + ln];
#pragma unroll
        for (int r = 0; r < 4; r++) {
            float o = siluf(sacc[t][r] + sb) * posD[t][r];
            zv[t][r] = o;
            part4[r] += o * aw;
        }
    }
    float ab = attb[0];
#pragma unroll
    for (int r = 0; r < 4; r++) {
        float sg = sigmf(quadSum(part4[r]) + ab);
        size_t row = m0 + q * 4 + r;
#pragma unroll
        for (int t = 0; t < 4; t++) {
            float z = zv[t][r] * sg;
            zv[t][r] = z;
            g_z16[row * 64 + t * 16 + ln] = f2bu(z);
        }
    }
#pragma unroll
    for (int hd = 0; hd < 4; hd++) {
#pragma unroll
        for (int r = 0; r < 4; r++) {
            float p = 0.f;
#pragma unroll
            for (int t = 0; t < 4; t++) p += zv[t][r] * sWB[hd * 64 + t * 16 + ln];
            p = quadSum(p);
            if (ln == hd) g_b4[(size_t)(m0 + q * 4 + r) * 4 + hd] = p;
        }
    }
#pragma unroll
    for (int t = 0; t < 4; t++)
#pragma unroll
        for (int r = 0; r < 4; r++)
            T[w][(q * 4 + r) * 72 + t * 16 + ln] = f2bu(posD[t][r]);
    asm volatile("s_waitcnt lgkmcnt(0)" ::: "memory");
    s16x8 pa0 = *(const s16x8*)(&T[w][ln * 72 + q * 8]);
    s16x8 pa1 = *(const s16x8*)(&T[w][ln * 72 + 32 + q * 8]);
    __syncthreads();
    stageP(sW0, g_wmA[3], tid); stageP(sW1b, g_wmA[4], tid); stageP(sW2b, g_wmA[5], tid);
    __syncthreads();
    f32x4 uacc[4];
#pragma unroll
    for (int t = 0; t < 4; t++) {
        f32x4 a = (f32x4){0,0,0,0};
        a = __builtin_amdgcn_mfma_f32_16x16x32_bf16(ca0, *(const s16x8*)(&sW0[(t * 16 + ln) * 72 + q * 8]), a, 0, 0, 0);
        a = __builtin_amdgcn_mfma_f32_16x16x32_bf16(ca1, *(const s16x8*)(&sW0[(t * 16 + ln) * 72 + 32 + q * 8]), a, 0, 0, 0);
        uacc[t] = a;
    }
    float up[4] = {0.f, 0.f, 0.f, 0.f};
#pragma unroll
    for (int t = 0; t < 4; t++) {
        float ub = ub1[t * 16 + ln];
        float w2 = uW2[t * 16 + ln];
#pragma unroll
        for (int r = 0; r < 4; r++) up[r] += siluf(uacc[t][r] + ub) * w2;
    }
    float ub2v = ub2[0];
    float pu[4];
#pragma unroll
    for (int r = 0; r < 4; r++) pu[r] = quadSum(up[r]) + ub2v;
    f32x4 xacc[4], nacc[4];
#pragma unroll
    for (int t = 0; t < 4; t++) {
        f32x4 a = (f32x4){0,0,0,0}, b = (f32x4){0,0,0,0};
        a = __builtin_amdgcn_mfma_f32_16x16x32_bf16(pa0, *(const s16x8*)(&sW1b[(t * 16 + ln) * 72 + q * 8]), a, 0, 0, 0);
        a = __builtin_amdgcn_mfma_f32_16x16x32_bf16(pa1, *(const s16x8*)(&sW1b[(t * 16 + ln) * 72 + 32 + q * 8]), a, 0, 0, 0);
        b = __builtin_amdgcn_mfma_f32_16x16x32_bf16(pa0, *(const s16x8*)(&sW2b[(t * 16 + ln) * 72 + q * 8]), b, 0, 0, 0);
        b = __builtin_amdgcn_mfma_f32_16x16x32_bf16(pa1, *(const s16x8*)(&sW2b[(t * 16 + ln) * 72 + 32 + q * 8]), b, 0, 0, 0);
        xacc[t] = a; nacc[t] = b;
    }
    float xp[4] = {0,0,0,0}, npv[4] = {0,0,0,0};
#pragma unroll
    for (int t = 0; t < 4; t++) {
        float xb = xb1[t * 16 + ln], nb = nb1[t * 16 + ln];
        float xw = xW2[t * 16 + ln], nw = nW2[t * 16 + ln];
#pragma unroll
        for (int r = 0; r < 4; r++) {
            xp[r] += siluf(xacc[t][r] + xb) * xw;
            npv[r] += siluf(nacc[t][r] + nb) * nw;
        }
    }
    float xb2v = xb2[0], nb2v = nb2[0];
#pragma unroll
    for (int r = 0; r < 4; r++) {
        float phix = quadSum(xp[r]) + xb2v;
        float phin = quadSum(npv[r]) + nb2v;
        int row = m0 + q * 4 + r;
        float tx = pu[r] * phix, tn = pu[r] * phin;
        int cc = edges[EE + row];
        if (ln < 3) {
            g_xe[row * 3 + ln] = g_cdl[row * 3 + ln] * tx;
            g_ne[row * 3 + ln] = nvecs[cc * 3 + ln] * tn;
        }
    }
}

// ---------------- attention + fused heads: 1-wave blocks, qp + 2-deep pipeline + in-block us ----------------
struct STG { s16x8 za0, za1, qb0, qb1; f32x4 bv; };

__global__ __launch_bounds__(64) void k_attn2(const int* __restrict__ klist,
                                              const float* __restrict__ bg)
{
    __shared__ __align__(16) u16 sQP[16][256];   // qp tile: [edge j][hd*64+d]; reused as u-tile in phase 3
    __shared__ __align__(16) u16 zT[16 * 72];
    __shared__ __align__(16) u16 sT4[4][16 * 72]; // t4 stash: [hd][j*72 + d]
    __shared__ __align__(16) float sA[4][16];
    int lane = threadIdx.x & 63, q = lane >> 4, ln = lane & 15;
    int m0 = blockIdx.x * 16;              // wave owns edges m0..m0+15
    u16* zw = zT;

    // ---- phase 1: qp = z[own] @ M for the 16 own edges (B-frags from global g_Mt, L2-hot) ----
    const u16* zro = g_z16 + (size_t)(m0 + ln) * 64;
    s16x8 zaf0 = *(const s16x8*)(zro + q * 8);       // own z A-fragments: live through phase 3
    s16x8 zaf1 = *(const s16x8*)(zro + 32 + q * 8);
    {
#pragma unroll
        for (int hd = 0; hd < 4; hd++) {
            f32x4 aM[4];
#pragma unroll
            for (int t = 0; t < 4; t++) {
                f32x4 a = (f32x4){0,0,0,0};
                a = __builtin_amdgcn_mfma_f32_16x16x32_bf16(zaf0, *(const s16x8*)(&g_Mt[hd][(t * 16 + ln) * 72 + q * 8]), a, 0, 0, 0);
                a = __builtin_amdgcn_mfma_f32_16x16x32_bf16(zaf1, *(const s16x8*)(&g_Mt[hd][(t * 16 + ln) * 72 + 32 + q * 8]), a, 0, 0, 0);
                aM[t] = a;
            }
#pragma unroll
            for (int t = 0; t < 4; t++)
#pragma unroll
                for (int r = 0; r < 4; r++)
                    sQP[q * 4 + r][hd * 64 + t * 16 + ln] = f2bu(aM[t][r]);
        }
    }
    asm volatile("s_waitcnt lgkmcnt(0)" ::: "memory");

    // ---- phase 2: attention over own 16 edges, 2-deep-ahead pipeline ----
    auto ldkl = [&](int j) -> int {
        return (lane < 32) ? klist[(size_t)(m0 + j) * 32 + lane] : -1;
    };
    auto stage = [&](int kv, int j) -> STG {
        STG s;
        s.za0 = (s16x8){0,0,0,0,0,0,0,0}; s.za1 = (s16x8){0,0,0,0,0,0,0,0};
        s.qb0 = (s16x8){0,0,0,0,0,0,0,0}; s.qb1 = (s16x8){0,0,0,0,0,0,0,0};
        int ij = __shfl(kv, ln);
        if (ij >= 0) {
            const u16* zr = g_z16 + (size_t)ij * 64;
            s.za0 = *(const s16x8*)(zr + q * 8);
            s.za1 = *(const s16x8*)(zr + 32 + q * 8);
        }
        if (ln < 4) {
            s.qb0 = *(const s16x8*)(&sQP[j][ln * 64 + q * 8]);
            s.qb1 = *(const s16x8*)(&sQP[j][ln * 64 + 32 + q * 8]);
        }
        s.bv = (f32x4){0.f, 0.f, 0.f, 0.f};
#pragma unroll
        for (int r = 0; r < 4; r++) {
            int ijj = __shfl(kv, q * 4 + r);
            int jj = __shfl(kv, 16 + q * 4 + r);
            s.bv[r] = (ijj >= 0 && ln < 4) ? g_b4[(size_t)jj * 4 + ln] : 0.f;
        }
        return s;
    };

    int kvA = ldkl(0), kvB = ldkl(1), kvC = ldkl(2);
    STG s0 = stage(kvA, 0);
    STG s1 = stage(kvB, 1);
#pragma unroll 1
    for (int j = 0; j < 16; j++) {
        int kvD = (j + 3 < 16) ? ldkl(j + 3) : -1;
        STG s2;
        if (j + 2 < 16) s2 = stage(kvC, j + 2);
        else {
            s2.za0 = (s16x8){0,0,0,0,0,0,0,0}; s2.za1 = s2.za0;
            s2.qb0 = s2.za0; s2.qb1 = s2.za0;
            s2.bv = (f32x4){0.f, 0.f, 0.f, 0.f};
        }
        // scores (validity folded: za=0 & bv=0 for masked slots -> s=0)
        f32x4 sc = (f32x4){0.f, 0.f, 0.f, 0.f};
        sc = __builtin_amdgcn_mfma_f32_16x16x32_bf16(s0.za0, s0.qb0, sc, 0, 0, 0);
        sc = __builtin_amdgcn_mfma_f32_16x16x32_bf16(s0.za1, s0.qb1, sc, 0, 0, 0);
        *(s16x8*)(&zw[ln * 72 + q * 8]) = s0.za0;
        *(s16x8*)(&zw[ln * 72 + 32 + q * 8]) = s0.za1;
        float s[4];
#pragma unroll
        for (int r = 0; r < 4; r++) s[r] = 0.125f * sc[r] + s0.bv[r];
        float mx = fmaxf(fmaxf(s[0], s[1]), fmaxf(s[2], s[3]));
        mx = fmaxf(mx, __shfl_xor(mx, 16));
        mx = fmaxf(mx, __shfl_xor(mx, 32));
        float ex[4], ps = 0.f;
#pragma unroll
        for (int r = 0; r < 4; r++) { ex[r] = __expf(s[r] - mx); ps += ex[r]; }
        ps += __shfl_xor(ps, 16);
        ps += __shfl_xor(ps, 32);
        float inv = 1.f / ps;
        if (ln < 4)
            *(f32x4*)&sA[ln][q * 4] = (f32x4){ex[0] * inv, ex[1] * inv, ex[2] * inv, ex[3] * inv};
        asm volatile("s_waitcnt lgkmcnt(0)" ::: "memory");
        float t0 = 0.f, t1 = 0.f, t2 = 0.f, t3 = 0.f;
#pragma unroll
        for (int j4 = 0; j4 < 4; j4++) {
            f32x4 a0 = *(const f32x4*)&sA[0][j4 * 4];
            f32x4 a1 = *(const f32x4*)&sA[1][j4 * 4];
            f32x4 a2 = *(const f32x4*)&sA[2][j4 * 4];
            f32x4 a3 = *(const f32x4*)&sA[3][j4 * 4];
#pragma unroll
            for (int r = 0; r < 4; r++) {
                float zz = us2f(zw[(j4 * 4 + r) * 72 + lane]);
                t0 += a0[r] * zz; t1 += a1[r] * zz; t2 += a2[r] * zz; t3 += a3[r] * zz;
            }
        }
        // stash t4 rows in LDS (replaces global t4 round-trip)
        sT4[0][j * 72 + lane] = f2bu(t0);
        sT4[1][j * 72 + lane] = f2bu(t1);
        sT4[2][j * 72 + lane] = f2bu(t2);
        sT4[3][j * 72 + lane] = f2bu(t3);
        kvA = kvB; kvB = kvC; kvC = kvD;
        s0 = s1; s1 = s2;
    }

    // ---- phase 3: fused heads  u=(t@Wv)*sigm(z@Wg+bg); m=Σ_hd u@oW_hd ----
    asm volatile("s_waitcnt lgkmcnt(0)" ::: "memory");
    u16* uT = &sQP[0][0];   // sQP dead after phase 2; reuse first 16*72 u16 as u-tile
    f32x4 macc[4];
#pragma unroll
    for (int t = 0; t < 4; t++) macc[t] = (f32x4){0,0,0,0};
    for (int hd = 0; hd < 4; hd++) {
        const u16* wV = g_wpre[hd * 3 + 0];
        const u16* wO = g_wpre[hd * 3 + 1];
        const u16* wG = g_wpre[hd * 3 + 2];
        f32x4 vacc[4], gacc[4];
#pragma unroll
        for (int t = 0; t < 4; t++) { vacc[t] = (f32x4){0,0,0,0}; gacc[t] = (f32x4){0,0,0,0}; }
#pragma unroll
        for (int k0 = 0; k0 < 2; k0++) {
            s16x8 af = *(const s16x8*)(&sT4[hd][ln * 72 + k0 * 32 + q * 8]);
            s16x8 zf = (k0 == 0) ? zaf0 : zaf1;
#pragma unroll
            for (int t = 0; t < 4; t++) {
                vacc[t] = __builtin_amdgcn_mfma_f32_16x16x32_bf16(
                    af, *(const s16x8*)(&wV[(t * 16 + ln) * 72 + k0 * 32 + q * 8]), vacc[t], 0, 0, 0);
                gacc[t] = __builtin_amdgcn_mfma_f32_16x16x32_bf16(
                    zf, *(const s16x8*)(&wG[(t * 16 + ln) * 72 + k0 * 32 + q * 8]), gacc[t], 0, 0, 0);
            }
        }
#pragma unroll
        for (int t = 0; t < 4; t++) {
            float bb = bg[hd * 64 + t * 16 + ln];
#pragma unroll
            for (int r = 0; r < 4; r++) {
                float u = vacc[t][r] * sigmf(gacc[t][r] + bb);
                uT[(q * 4 + r) * 72 + t * 16 + ln] = f2bu(u);
            }
        }
        asm volatile("s_waitcnt lgkmcnt(0)" ::: "memory");
#pragma unroll
        for (int k0 = 0; k0 < 2; k0++) {
            s16x8 af = *(const s16x8*)(&uT[ln * 72 + k0 * 32 + q * 8]);
#pragma unroll
            for (int t = 0; t < 4; t++) {
                macc[t] = __builtin_amdgcn_mfma_f32_16x16x32_bf16(
                    af, *(const s16x8*)(&wO[(t * 16 + ln) * 72 + k0 * 32 + q * 8]), macc[t], 0, 0, 0);
            }
        }
        asm volatile("s_waitcnt lgkmcnt(0)" ::: "memory");
    }
#pragma unroll
    for (int r = 0; r < 4; r++) {
        size_t dst = (size_t)(m0 + q * 4 + r) * 64;
#pragma unroll
        for (int t = 0; t < 4; t++) g_me16[dst + t * 16 + ln] = f2bu(macc[t][r]);
    }
}

// ---------------- CSR aggregation: one wave per node; m mean + coord/nvec finalize ----------------
__global__ __launch_bounds__(256) void k_agg(
    const float* __restrict__ coord, const float* __restrict__ nvecs,
    const float* __restrict__ icoord, const float* __restrict__ invecs,
    const float* __restrict__ ob, float* __restrict__ out)
{
    int tid = threadIdx.x;
    int lane = tid & 63;
    int n = blockIdx.x * 4 + (tid >> 6);
    if (n >= NN) return;
    int r0 = g_roff[n], r1 = g_roff[n + 1];
    int deg = r1 - r0;
    float msA = 0.f, msB = 0.f, msC = 0.f, msD = 0.f;
    float xs0 = 0.f, xs1 = 0.f, xs2 = 0.f, ns0 = 0.f, ns1 = 0.f, ns2 = 0.f;
    for (int base = r0; base < r1; base += 64) {
        int idx = base + lane;
        int e_l = (idx < r1) ? g_eid[idx] : -1;
        int cnt = min(64, r1 - base);
        int j = 0;
        for (; j + 3 < cnt; j += 4) {
            int ea = __shfl(e_l, j), eb = __shfl(e_l, j + 1);
            int ec = __shfl(e_l, j + 2), ed = __shfl(e_l, j + 3);
            msA += us2f(g_me16[(size_t)ea * 64 + lane]);
            msB += us2f(g_me16[(size_t)eb * 64 + lane]);
            msC += us2f(g_me16[(size_t)ec * 64 + lane]);
            msD += us2f(g_me16[(size_t)ed * 64 + lane]);
        }
        for (; j < cnt; j++) {
            int ea = __shfl(e_l, j);
            msA += us2f(g_me16[(size_t)ea * 64 + lane]);
        }
        if (e_l >= 0) {
            xs0 += g_xe[e_l * 3 + 0]; xs1 += g_xe[e_l * 3 + 1]; xs2 += g_xe[e_l * 3 + 2];
            ns0 += g_ne[e_l * 3 + 0]; ns1 += g_ne[e_l * 3 + 1]; ns2 += g_ne[e_l * 3 + 2];
        }
    }
    xs0 = waveSum(xs0); xs1 = waveSum(xs1); xs2 = waveSum(xs2);
    ns0 = waveSum(ns0); ns1 = waveSum(ns1); ns2 = waveSum(ns2);
    float rinv = 1.f / fmaxf((float)deg, 1.f);
    float obv = (deg > 0) ? ob[lane] : 0.f;
    g_mavg[(size_t)n * 64 + lane] = (msA + msB + msC + msD) * rinv + obv;
    if (lane == 0) {
        size_t coff = (size_t)NN * 64;
        size_t noff = coff + (size_t)NN * 3;
        float xs[3] = {xs0, xs1, xs2}, ns[3] = {ns0, ns1, ns2};
        float nl[3];
#pragma unroll
        for (int c = 0; c < 3; c++) {
            out[coff + n * 3 + c] = 0.2f * icoord[n * 3 + c] + 0.8f * coord[n * 3 + c] + xs[c] * rinv;
            nl[c] = 0.2f * invecs[n * 3 + c] + 0.8f * nvecs[n * 3 + c] + ns[c] * rinv;
        }
        float nn2 = sqrtf(nl[0] * nl[0] + nl[1] * nl[1] + nl[2] * nl[2]) + 1e-8f;
#pragma unroll
        for (int c = 0; c < 3; c++) out[noff + n * 3 + c] = nl[c] / nn2;
    }
}

// ---------------- node finalize: MFMA MLP over [h|na|m_agg] ----------------
__global__ __launch_bounds__(256) void k_node(
    const float* __restrict__ h, const float* __restrict__ na,
    const float* __restrict__ W1, const float* __restrict__ b1,
    const float* __restrict__ W2, const float* __restrict__ b2,
    float* __restrict__ out)
{
    __shared__ u16 sW1T[64 * 200];
    __shared__ u16 sW2T[64 * 72];
    __shared__ u16 sA[64 * 200];
    __shared__ u16 sT[64 * 72];
    __shared__ float sb2v[64];
    int tid = threadIdx.x;
    int m0 = blockIdx.x * 64;
    for (int i = tid; i < 64 * 192; i += 256) {
        int n = i / 192, k = i - n * 192;
        sW1T[n * 200 + k] = f2bu(W1[k * 64 + n]);
    }
    for (int i = tid; i < 4096; i += 256) {
        int k = i >> 6, n = i & 63;
        sW2T[n * 72 + k] = f2bu(W2[i]);
    }
    if (tid < 64) sb2v[tid] = b2[tid];
    for (int i = tid; i < 4096; i += 256) {
        int row = i >> 6, d = i & 63;
        int n = m0 + row; if (n >= NN) n = NN - 1;
        sA[row * 200 + d] = f2bu(h[(size_t)n * 64 + d]);
        sA[row * 200 + 64 + d] = f2bu(na[(size_t)n * 64 + d]);
        sA[row * 200 + 128 + d] = f2bu(g_mavg[(size_t)n * 64 + d]);
    }
    __syncthreads();
    int lane = tid & 63, q = lane >> 4, ln = lane & 15, w = tid >> 6;
    f32x4 acc[4];
#pragma unroll
    for (int t = 0; t < 4; t++) acc[t] = (f32x4){0.f, 0.f, 0.f, 0.f};
#pragma unroll
    for (int k0 = 0; k0 < 6; k0++) {
        s16x8 af = *(const s16x8*)(&sA[(w * 16 + ln) * 200 + k0 * 32 + q * 8]);
#pragma unroll
        for (int t = 0; t < 4; t++) {
            s16x8 bf = *(const s16x8*)(&sW1T[(t * 16 + ln) * 200 + k0 * 32 + q * 8]);
            acc[t] = __builtin_amdgcn_mfma_f32_16x16x32_bf16(af, bf, acc[t], 0, 0, 0);
        }
    }
#pragma unroll
    for (int t = 0; t < 4; t++) {
        float bv = b1[t * 16 + ln];
#pragma unroll
        for (int r = 0; r < 4; r++)
            sT[(w * 16 + q * 4 + r) * 72 + t * 16 + ln] = f2bu(siluf(acc[t][r] + bv));
    }
    asm volatile("s_waitcnt lgkmcnt(0)" ::: "memory");
    f32x4 acc2[4];
#pragma unroll
    for (int t = 0; t < 4; t++) acc2[t] = (f32x4){0.f, 0.f, 0.f, 0.f};
#pragma unroll
    for (int k0 = 0; k0 < 2; k0++) {
        s16x8 af = *(const s16x8*)(&sT[(w * 16 + ln) * 72 + k0 * 32 + q * 8]);
#pragma unroll
        for (int t = 0; t < 4; t++) {
            s16x8 bf = *(const s16x8*)(&sW2T[(t * 16 + ln) * 72 + k0 * 32 + q * 8]);
            acc2[t] = __builtin_amdgcn_mfma_f32_16x16x32_bf16(af, bf, acc2[t], 0, 0, 0);
        }
    }
#pragma unroll
    for (int r = 0; r < 4; r++) {
        int n = m0 + w * 16 + q * 4 + r;
        if (n < NN) {
#pragma unroll
            for (int t = 0; t < 4; t++) {
                int d = t * 16 + ln;
                out[(size_t)n * 64 + d] = 0.2f * h[(size_t)n * 64 + d] + 0.8f * (acc2[t][r] + sb2v[d]);
            }
        }
    }
}

extern "C" void kernel_launch(void* const* d_in, const int* in_sizes, int n_in,
                              void* d_out, int out_size, void* d_ws, size_t ws_size,
                              hipStream_t stream)
{
    const int* edges = (const int*)d_in[43];
    const int* klist = (const int*)d_in[44];
    auto F = [&](int i) { return (const float*)d_in[i]; };

    k_zero<<<40, 256, 0, stream>>>();
    k_prep<<<512, 256, 0, stream>>>(F(19), F(20), F(0), F(4), F(3), F(1), F(2),
                                    F(21), F(23), F(25),
                                    F(13), F(9), F(15), F(27), F(31), F(35), F(7),
                                    edges);
    k_scan<<<1, 256, 0, stream>>>();
    k_fill<<<782, 256, 0, stream>>>(edges);
    k_chem1<<<1563, 256, 0, stream>>>(edges, F(8));
    k_megaAB<<<3125, 256, 0, stream>>>(F(10), F(11), F(12), F(14),
                                       F(16), F(17), F(18), F(22),
                                       F(28), F(29), F(30),
                                       F(32), F(33), F(34),
                                       F(36), F(37), F(38),
                                       edges, F(2));
    k_attn2<<<12500, 64, 0, stream>>>(klist, F(24));
    k_agg<<<2500, 256, 0, stream>>>(F(1), F(2), F(5), F(6), F(26), (float*)d_out);
    k_node<<<157, 256, 0, stream>>>(F(0), F(4), F(39), F(40), F(41), F(42), (float*)d_out);
}